// Round 2
// baseline (354.304 us; speedup 1.0000x reference)
//
#include <hip/hip_runtime.h>
#include <hip/hip_bf16.h>
#include <math.h>

#define Bx   256
#define Nx   512
#define SIGx 256
#define HIDx 256
#define OUTx 10
#define Hx   256

typedef __attribute__((ext_vector_type(4))) float f32x4;
typedef long fp8x8;          // 8 fp8 bytes = 2 VGPRs (MFMA A/B operand)
typedef unsigned char uchar;

__device__ inline uchar f2fp8(float v) {
    int r = __builtin_amdgcn_cvt_pk_fp8_f32(v, 0.0f, 0, false);
    return (uchar)(r & 0xff);
}
__device__ inline uint pk4fp8(float a0, float a1, float a2, float a3) {
    int r = __builtin_amdgcn_cvt_pk_fp8_f32(a0, a1, 0, false);
    r = __builtin_amdgcn_cvt_pk_fp8_f32(a2, a3, r, true);
    return (uint)r;
}

// async global->LDS, 16B per lane; lds dest = wave-uniform base + lane*16
__device__ inline void gload_lds16(const uchar* g, uchar* l) {
    __builtin_amdgcn_global_load_lds(
        (const __attribute__((address_space(1))) uint*)g,
        (__attribute__((address_space(3))) uint*)l, 16, 0, 0);
}
// swizzled LDS fragment address: 64B rows, 16B-unit XOR swizzle
__device__ inline const uchar* laddr(const uchar* base, int row, int kb) {
    int ps = (kb >> 4) ^ ((row >> 1) & 3) ^ ((row >> 4) & 3);
    return base + row*64 + ps*16 + (kb & 15);
}

// ---------------------------------------------------------------------------
// Kernel A: sampling stage (mixture fields constant over m => unif dead).
// ---------------------------------------------------------------------------
__global__ __launch_bounds__(512) void kA_sample(
    const float* __restrict__ x, const float* __restrict__ z,
    const float* __restrict__ mg, float* __restrict__ feat,
    float* __restrict__ flp)
{
    int b = blockIdx.x;
    int n = threadIdx.x;
    int g = n >> 5;
    float mux = mg[g*6+1];
    float muy = mg[g*6+2];
    float sxv = expf(mg[g*6+3]);
    float syv = expf(mg[g*6+4]);
    float rho = tanhf(mg[g*6+5]);
    float z1 = z[((size_t)b*Nx + n)*2 + 0];
    float z2 = z[((size_t)b*Nx + n)*2 + 1];
    float omr2 = 1.0f - rho*rho;
    float xs = mux + sxv*z1;
    float ys = muy + syv*(rho*z1 + sqrtf(omr2)*z2);
    float dx = xs - mux, dy = ys - muy;
    float quad = (dx*dx/(sxv*sxv) - 2.0f*rho*dx*dy/(sxv*syv) + dy*dy/(syv*syv)) / omr2;
    float logprob = -1.8378770664093453f - logf(sxv*syv) - 0.5f*logf(omr2) - 0.5f*quad;
    float lx = tanhf(xs), ly = tanhf(ys);
    int px = (int)truncf(0.5f*(lx+1.0f)*(float)Hx - 0.1f);
    int py = (int)truncf(0.5f*(ly+1.0f)*(float)Hx - 0.1f);
    px = px < 0 ? 0 : (px > Hx-1 ? Hx-1 : px);
    py = py < 0 ? 0 : (py > Hx-1 ? Hx-1 : py);
    float pv = x[(size_t)b*Hx*Hx + (size_t)px*Hx + py];
    size_t fo = ((size_t)b*Nx + n)*3;
    feat[fo+0] = pv; feat[fo+1] = lx; feat[fo+2] = ly;

    __shared__ float red[512];
    red[n] = logprob;
    __syncthreads();
    for (int st = 256; st > 0; st >>= 1) {
        if (n < st) red[n] += red[n+st];
        __syncthreads();
    }
    if (n == 0) flp[b] = red[0];
}

// ---------------------------------------------------------------------------
// Prep: c1,c2 -> fp8 (x16 scale); w2 -> w2t fp8 (x16, transposed).
// ---------------------------------------------------------------------------
__global__ __launch_bounds__(256) void kPrep(
    const float* __restrict__ c1, const float* __restrict__ c2,
    const float* __restrict__ w2,
    uchar* __restrict__ c1q, uchar* __restrict__ c2q, uchar* __restrict__ w2tq)
{
    int idx = blockIdx.x*256 + threadIdx.x;
    if (idx < SIGx*Nx) {
        c1q[idx] = f2fp8(16.0f * c1[idx]);
        c2q[idx] = f2fp8(16.0f * c2[idx]);
    }
    if (idx < HIDx*HIDx) {
        int i = idx >> 8, j = idx & 255;
        w2tq[idx] = f2fp8(16.0f * w2[j*HIDx + i]);
    }
}

// ===========================================================================
// kFuse1: per b -- rank-3 accumulation G[c][n] = sum_m featT[c][m]*adj[m][n]
// (adj NOT materialized), epilogue s1t[h][n]=relu(w1.G+b1)->fp8.
// Also emits locp[n] = (lx, ly, hx, cn) so downstream recomputes adj.
// ===========================================================================
__global__ __launch_bounds__(512) void kFuse1(
    const float* __restrict__ featL, const float* __restrict__ w1,
    const float* __restrict__ b1,
    f32x4* __restrict__ locpL, uchar* __restrict__ s1tAll)
{
    int b = blockIdx.x;
    const float* fb = featL + (size_t)b*Nx*3;
    f32x4* locb = locpL + (size_t)b*Nx;
    uchar* s1t = s1tAll + (size_t)b*HIDx*Nx;

    __shared__ float fpv[Nx], flx[Nx], fly[Nx], fH[Nx];
    __shared__ float w1s[3*HIDx], b1s[HIDx];
    __shared__ float Gp[4][3][Nx];

    int t = threadIdx.x;
    {
        float pv = fb[t*3+0], lx = fb[t*3+1], ly = fb[t*3+2];
        fpv[t] = pv; flx[t] = lx; fly[t] = ly;
        float hx = fmaf(0.5f*lx, lx, fmaf(0.5f*ly, ly, 1.0f));
        fH[t] = hx;
        locb[t] = (f32x4){lx, ly, hx, fmaf(0.5f*lx, lx, 0.5f*ly*ly)};
    }
    for (int i = t; i < 3*HIDx; i += 512) w1s[i] = w1[i];
    if (t < HIDx) b1s[t] = b1[t];
    __syncthreads();

    int tq = t & 127;          // column-quad index: n = 4*tq .. 4*tq+3
    int mc = t >> 7;           // m-chunk 0..3 (128 m each)
    int n4 = tq*4;

    float xn[4], yn[4], cn[4];
    #pragma unroll
    for (int e = 0; e < 4; ++e) {
        xn[e] = flx[n4+e]; yn[e] = fly[n4+e];
        cn[e] = fmaf(0.5f*xn[e], xn[e], 0.5f*yn[e]*yn[e]);
    }
    float G0[4] = {}, G1[4] = {}, G2[4] = {};

    int m0 = mc*128;
    #pragma unroll 4
    for (int mm = 0; mm < 128; ++mm) {
        int m = m0 + mm;
        float hx = fH[m], fx = flx[m], fy = fly[m];
        float a[4];
        #pragma unroll
        for (int e = 0; e < 4; ++e) {
            float s = fmaf(-yn[e], fy, fmaf(-xn[e], fx, hx + cn[e]));
            a[e] = __builtin_amdgcn_rcpf(s);
            G0[e] = fmaf(a[e], fpv[m], G0[e]);
            G1[e] = fmaf(a[e], fx, G1[e]);
            G2[e] = fmaf(a[e], fy, G2[e]);
        }
    }

    *(f32x4*)&Gp[mc][0][n4] = (f32x4){G0[0],G0[1],G0[2],G0[3]};
    *(f32x4*)&Gp[mc][1][n4] = (f32x4){G1[0],G1[1],G1[2],G1[3]};
    *(f32x4*)&Gp[mc][2][n4] = (f32x4){G2[0],G2[1],G2[2],G2[3]};
    __syncthreads();

    f32x4 T0 = {}, T1 = {}, T2 = {};
    #pragma unroll
    for (int j = 0; j < 4; ++j) {
        T0 += *(const f32x4*)&Gp[j][0][n4];
        T1 += *(const f32x4*)&Gp[j][1][n4];
        T2 += *(const f32x4*)&Gp[j][2][n4];
    }

    int hc = mc;
    #pragma unroll 4
    for (int hh = 0; hh < 64; ++hh) {
        int h = hc*64 + hh;
        float w0 = w1s[h], wA = w1s[HIDx+h], wB = w1s[2*HIDx+h], bb = b1s[h];
        float v0 = fminf(fmaxf(fmaf(T0.x,w0, fmaf(T1.x,wA, fmaf(T2.x,wB, bb))), 0.0f), 448.0f);
        float v1 = fminf(fmaxf(fmaf(T0.y,w0, fmaf(T1.y,wA, fmaf(T2.y,wB, bb))), 0.0f), 448.0f);
        float v2 = fminf(fmaxf(fmaf(T0.z,w0, fmaf(T1.z,wA, fmaf(T2.z,wB, bb))), 0.0f), 448.0f);
        float v3 = fminf(fmaxf(fmaf(T0.w,w0, fmaf(T1.w,wA, fmaf(T2.w,wB, bb))), 0.0f), 448.0f);
        *(uint*)(s1t + (size_t)h*Nx + n4) = pk4fp8(v0, v1, v2, v3);
    }
}

// ===========================================================================
// kGemmAdjM: s2t[h][n] = 0.25*relu(sum_m h2t[h][m]*adj[m][n]+b2[h]).
// rt-MERGED: each block computes ALL 256 h rows for one 128-col stripe, so
// the adj B-tile recompute runs once (not twice) per (b,ct,kk).
// Double-buffered LDS, ONE barrier per K-step: stage A[k+1] (async) +
// recompute B[k+1] overlap MFMA on buffers[cur] (independent streams).
// adj fp8 is bit-identical to the materialized path.
// ===========================================================================
__global__ __launch_bounds__(256) void kGemmAdjM(
    const uchar* __restrict__ Aall, const f32x4* __restrict__ locp,
    const float* __restrict__ bias, uchar* __restrict__ outAll)
{
    int b  = blockIdx.x;
    int ct = blockIdx.y;
    const uchar* A = Aall + (size_t)b*HIDx*Nx;
    const f32x4* locB = locp + (size_t)b*Nx;
    uchar* outp = outAll + (size_t)b*HIDx*Nx;

    __shared__ __align__(16) uchar Als[2][256*64];   // 32 KB (all 256 A rows)
    __shared__ __align__(16) uchar Bls[2][128*72];   // 18 KB (72B rows, 8B-aligned)
    int t = threadIdx.x;
    int lane = t & 63, wave = t >> 6;
    int wr = wave >> 1, wc = wave & 1;
    int q = lane >> 4, c16 = lane & 15;
    int n0 = ct*128;
    int lrow = lane >> 2;      // row-within-chunk for A staging
    int pu   = lane & 3;       // 16B-unit within row

    // B-recompute ownership: thread owns n-row (t&127), k-half (t>>7)*32.
    int row = t & 127;
    int kb0 = __builtin_amdgcn_readfirstlane((t >> 7) * 32);
    f32x4 nd = locB[n0 + row];
    float xn = nd.x, yn = nd.y, cnv = nd.w;

    f32x4 acc[2][4][4] = {};

    auto stageA = [&](int buf, int kkv) {
        #pragma unroll
        for (int r = 0; r < 4; ++r) {
            int chunk = wave*4 + r;
            int srow = chunk*16 + lrow;
            int sl = pu ^ ((srow>>1)&3) ^ ((srow>>4)&3);
            gload_lds16(A + (size_t)srow*Nx + kkv + sl*16, Als[buf] + chunk*1024);
        }
    };
    auto recompB = [&](int buf, int kkv) {
        const f32x4* mp = locB + kkv + kb0;
        uchar* brow = Bls[buf] + row*72;
        #pragma unroll
        for (int i = 0; i < 8; ++i) {
            f32x4 m0 = mp[i*4+0], m1 = mp[i*4+1], m2 = mp[i*4+2], m3 = mp[i*4+3];
            float s0 = fmaf(-yn, m0.y, fmaf(-xn, m0.x, m0.z + cnv));
            float s1 = fmaf(-yn, m1.y, fmaf(-xn, m1.x, m1.z + cnv));
            float s2 = fmaf(-yn, m2.y, fmaf(-xn, m2.x, m2.z + cnv));
            float s3 = fmaf(-yn, m3.y, fmaf(-xn, m3.x, m3.z + cnv));
            *(uint*)(brow + kb0 + i*4) = pk4fp8(
                __builtin_amdgcn_rcpf(s0), __builtin_amdgcn_rcpf(s1),
                __builtin_amdgcn_rcpf(s2), __builtin_amdgcn_rcpf(s3));
        }
    };
    auto mfmaHalf = [&](int buf, int ks) {
        const uchar* Ac = Als[buf];
        const uchar* Bc = Bls[buf];
        fp8x8 bfr[4];
        #pragma unroll
        for (int j = 0; j < 4; ++j)
            bfr[j] = *(const fp8x8*)(Bc + (size_t)(wc*64 + j*16 + c16)*72 + ks + q*8);
        #pragma unroll
        for (int rt = 0; rt < 2; ++rt) {
            fp8x8 af[4];
            #pragma unroll
            for (int i = 0; i < 4; ++i)
                af[i] = *(const fp8x8*)laddr(Ac, rt*128 + wr*64 + i*16 + c16, ks + q*8);
            #pragma unroll
            for (int i = 0; i < 4; ++i)
                #pragma unroll
                for (int j = 0; j < 4; ++j)
                    acc[rt][i][j] = __builtin_amdgcn_mfma_f32_16x16x32_fp8_fp8(
                        af[i], bfr[j], acc[rt][i][j], 0, 0, 0);
        }
    };

    // prologue
    stageA(0, 0);
    recompB(0, 0);
    __syncthreads();

    int cur = 0;
    for (int kk = 0; kk < Nx; kk += 64) {
        int nxt = cur ^ 1;
        bool more = (kk + 64) < Nx;
        if (more) stageA(nxt, kk + 64);     // async loads fly over the MFMAs
        mfmaHalf(cur, 0);
        if (more) recompB(nxt, kk + 64);    // VALU stream overlaps matrix pipe
        mfmaHalf(cur, 32);
        __syncthreads();                    // drains vmcnt; flips buffers
        cur = nxt;
    }

    #pragma unroll
    for (int rt = 0; rt < 2; ++rt)
        #pragma unroll
        for (int i = 0; i < 4; ++i) {
            int rowb = rt*128 + wr*64 + i*16 + q*4;
            #pragma unroll
            for (int j = 0; j < 4; ++j) {
                int col = n0 + wc*64 + j*16 + c16;
                #pragma unroll
                for (int r = 0; r < 4; ++r) {
                    float v = fmaxf(acc[rt][i][j][r] + bias[rowb + r], 0.0f) * 0.25f;
                    outp[(size_t)(rowb + r)*Nx + col] = f2fp8(fminf(v, 448.0f));
                }
            }
        }
}

// ---------------------------------------------------------------------------
// kGstdQ: C[row][col] = oscale * sum_k A[row][k]*B[k][col], fp8 in/out.
// A async-staged (swizzled). B: non-TRB async; TRB = VGPR transpose staging
// into the same swizzled layout. Grid (BC, tiles) b-major.
// ---------------------------------------------------------------------------
template<int K, int NC, bool TRB>
__global__ __launch_bounds__(256) void kGstdQ(
    const uchar* __restrict__ Ash, const uchar* __restrict__ Ball,
    uchar* __restrict__ outAll, float oscale)
{
    constexpr int CT = NC / 128;
    int b    = blockIdx.x;
    int tile = blockIdx.y;
    int rt = tile / CT;
    int ct = tile % CT;
    const uchar* B = Ball + (size_t)b*HIDx*Nx;
    uchar* outp = outAll + (size_t)b*HIDx*NC;

    __shared__ __align__(16) uchar Als[128*64];
    __shared__ __align__(16) uchar Bls[128*64];
    int t = threadIdx.x;
    int lane = t & 63, wave = t >> 6;
    int wr = wave >> 1, wc = wave & 1;
    int q = lane >> 4, c16 = lane & 15;
    int r0 = rt*128, n0 = ct*128;
    int lrow = lane >> 2;
    int pu   = lane & 3;
    f32x4 acc[4][4] = {};

    for (int kk = 0; kk < K; kk += 64) {
        #pragma unroll
        for (int r = 0; r < 2; ++r) {
            int chunk = wave*2 + r;
            int row = chunk*16 + lrow;
            int sl = pu ^ ((row>>1)&3) ^ ((row>>4)&3);
            gload_lds16(Ash + (size_t)(r0+row)*K + kk + sl*16, Als + chunk*1024);
            if (!TRB)
                gload_lds16(B + (size_t)(n0+row)*K + kk + sl*16, Bls + chunk*1024);
        }
        if (TRB) {
            int pi  = t & 31;          // k-pair within 64-k tile
            int nc8 = t >> 5;          // 8 col-groups of 16
            int hk = kk + 2*pi;
            const uchar* g0 = B + (size_t)hk*NC + n0 + nc8*16;
            const uchar* g1 = g0 + NC;
            float4 v0 = *(const float4*)g0;
            float4 v1 = *(const float4*)g1;
            const uchar* pa = (const uchar*)&v0;
            const uchar* qa = (const uchar*)&v1;
            int kb = 2*pi;
            int s  = kb >> 4;
            #pragma unroll
            for (int e = 0; e < 16; ++e) {
                int row = nc8*16 + e;
                int ps = s ^ ((row>>1)&3) ^ ((row>>4)&3);
                *(ushort*)(Bls + row*64 + ps*16 + (kb & 15)) =
                    (ushort)pa[e] | ((ushort)qa[e] << 8);
            }
        }
        __syncthreads();
        #pragma unroll
        for (int ks = 0; ks < 64; ks += 32) {
            fp8x8 af[4], bfr[4];
            #pragma unroll
            for (int i = 0; i < 4; ++i)
                af[i] = *(const fp8x8*)laddr(Als, wr*64 + i*16 + c16, ks + q*8);
            #pragma unroll
            for (int j = 0; j < 4; ++j)
                bfr[j] = *(const fp8x8*)laddr(Bls, wc*64 + j*16 + c16, ks + q*8);
            #pragma unroll
            for (int i = 0; i < 4; ++i)
                #pragma unroll
                for (int j = 0; j < 4; ++j)
                    acc[i][j] = __builtin_amdgcn_mfma_f32_16x16x32_fp8_fp8(af[i], bfr[j], acc[i][j], 0, 0, 0);
        }
        __syncthreads();
    }
    #pragma unroll
    for (int i = 0; i < 4; ++i) {
        int rowb = r0 + wr*64 + i*16 + q*4;
        #pragma unroll
        for (int j = 0; j < 4; ++j) {
            int col = n0 + wc*64 + j*16 + c16;
            #pragma unroll
            for (int r = 0; r < 4; ++r) {
                float v = acc[i][j][r] * oscale;
                v = fminf(fmaxf(v, -448.0f), 448.0f);
                outp[(size_t)(rowb + r)*NC + col] = f2fp8(v);
            }
        }
    }
}

// ---------------------------------------------------------------------------
// F1: single-pass online softmax-over-b stats for fp8 t1,t2. m and 1/d out.
// ---------------------------------------------------------------------------
__global__ __launch_bounds__(512) void kF1q(
    const uchar* __restrict__ t1, const uchar* __restrict__ t2,
    float* __restrict__ m1, float* __restrict__ rd1,
    float* __restrict__ m2, float* __restrict__ rd2)
{
    int s = blockIdx.x;
    int t = threadIdx.x;
    int hq = t & 63;
    int bq = t >> 6;
    const size_t str = (size_t)SIGx*HIDx;
    size_t base = (size_t)(bq*32)*str + (size_t)s*HIDx + hq*4;

    float mv1[4], dv1[4], mv2[4], dv2[4];
    #pragma unroll
    for (int e = 0; e < 4; ++e) { mv1[e]=-3.0e38f; dv1[e]=0.0f; mv2[e]=-3.0e38f; dv2[e]=0.0f; }

    for (int i = 0; i < 32; ++i) {
        uint u1 = *(const uint*)(t1 + base + (size_t)i*str);
        uint u2 = *(const uint*)(t2 + base + (size_t)i*str);
        float v1[4], v2[4];
        v1[0] = __builtin_amdgcn_cvt_f32_fp8(u1, 0);
        v1[1] = __builtin_amdgcn_cvt_f32_fp8(u1, 1);
        v1[2] = __builtin_amdgcn_cvt_f32_fp8(u1, 2);
        v1[3] = __builtin_amdgcn_cvt_f32_fp8(u1, 3);
        v2[0] = __builtin_amdgcn_cvt_f32_fp8(u2, 0);
        v2[1] = __builtin_amdgcn_cvt_f32_fp8(u2, 1);
        v2[2] = __builtin_amdgcn_cvt_f32_fp8(u2, 2);
        v2[3] = __builtin_amdgcn_cvt_f32_fp8(u2, 3);
        #pragma unroll
        for (int e = 0; e < 4; ++e) {
            float mn;
            mn = fmaxf(mv1[e], v1[e]);
            dv1[e] = dv1[e]*__expf(mv1[e]-mn) + __expf(v1[e]-mn); mv1[e] = mn;
            mn = fmaxf(mv2[e], v2[e]);
            dv2[e] = dv2[e]*__expf(mv2[e]-mn) + __expf(v2[e]-mn); mv2[e] = mn;
        }
    }

    __shared__ float pm1[8][256], pd1[8][256], pm2[8][256], pd2[8][256];
    #pragma unroll
    for (int e = 0; e < 4; ++e) {
        pm1[bq][hq*4+e] = mv1[e]; pd1[bq][hq*4+e] = dv1[e];
        pm2[bq][hq*4+e] = mv2[e]; pd2[bq][hq*4+e] = dv2[e];
    }
    __syncthreads();

    if (t < 256) {
        int h = t;
        float m = -3.0e38f, d = 0.0f;
        #pragma unroll
        for (int j = 0; j < 8; ++j) {
            float mm = pm1[j][h], dd = pd1[j][h];
            float mn = fmaxf(m, mm);
            d = d*__expf(m-mn) + dd*__expf(mm-mn);
            m = mn;
        }
        size_t o = (size_t)s*HIDx + h;
        m1[o] = m; rd1[o] = 1.0f/d;
    } else {
        int h = t - 256;
        float m = -3.0e38f, d = 0.0f;
        #pragma unroll
        for (int j = 0; j < 8; ++j) {
            float mm = pm2[j][h], dd = pd2[j][h];
            float mn = fmaxf(m, mm);
            d = d*__expf(m-mn) + dd*__expf(mm-mn);
            m = mn;
        }
        size_t o = (size_t)s*HIDx + h;
        m2[o] = m; rd2[o] = 1.0f/d;
    }
}

// ---------------------------------------------------------------------------
// F2: sig[b,s] = sum_h exp(t1-m1)*rd1 + exp(t2-m2)*rd2 (fp8 t).
// ---------------------------------------------------------------------------
__global__ __launch_bounds__(256) void kF2q(
    const uchar* __restrict__ t1, const uchar* __restrict__ t2,
    const float* __restrict__ m1, const float* __restrict__ rd1,
    const float* __restrict__ m2, const float* __restrict__ rd2,
    float* __restrict__ sig)
{
    int b = blockIdx.y;
    int sq = threadIdx.x >> 6;
    int s = blockIdx.x*4 + sq;
    int hq = threadIdx.x & 63;
    size_t sh = (size_t)s*HIDx + hq*4;
    size_t tb = ((size_t)b*SIGx + s)*HIDx + hq*4;
    uint u1 = *(const uint*)(t1 + tb);
    uint u2 = *(const uint*)(t2 + tb);
    f32x4 a1 = *(const f32x4*)&m1[sh];
    f32x4 r1 = *(const f32x4*)&rd1[sh];
    f32x4 a2 = *(const f32x4*)&m2[sh];
    f32x4 r2 = *(const f32x4*)&rd2[sh];
    float v = 0.0f;
    v += __expf(__builtin_amdgcn_cvt_f32_fp8(u1,0) - a1.x) * r1.x;
    v += __expf(__builtin_amdgcn_cvt_f32_fp8(u1,1) - a1.y) * r1.y;
    v += __expf(__builtin_amdgcn_cvt_f32_fp8(u1,2) - a1.z) * r1.z;
    v += __expf(__builtin_amdgcn_cvt_f32_fp8(u1,3) - a1.w) * r1.w;
    v += __expf(__builtin_amdgcn_cvt_f32_fp8(u2,0) - a2.x) * r2.x;
    v += __expf(__builtin_amdgcn_cvt_f32_fp8(u2,1) - a2.y) * r2.y;
    v += __expf(__builtin_amdgcn_cvt_f32_fp8(u2,2) - a2.z) * r2.z;
    v += __expf(__builtin_amdgcn_cvt_f32_fp8(u2,3) - a2.w) * r2.w;

    __shared__ float red[256];
    red[threadIdx.x] = v;
    __syncthreads();
    for (int st = 32; st > 0; st >>= 1) {
        if (hq < st) red[threadIdx.x] += red[threadIdx.x + st];
        __syncthreads();
    }
    if (hq == 0) sig[(size_t)b*SIGx + s] = red[sq*64];
}

// ---------------------------------------------------------------------------
// G: out[b,:] = softmax(sig[b,:] @ fcf_w.T + fcf_b)
// ---------------------------------------------------------------------------
__global__ __launch_bounds__(256) void kG_out(
    const float* __restrict__ sig, const float* __restrict__ fw,
    const float* __restrict__ fb, float* __restrict__ out)
{
    int b = blockIdx.x;
    int tid = threadIdx.x;
    __shared__ float red[256];
    __shared__ float logits[OUTx];
    float sv = sig[(size_t)b*SIGx + tid];
    for (int o = 0; o < OUTx; ++o) {
        red[tid] = sv * fw[o*SIGx + tid];
        __syncthreads();
        for (int st = 128; st > 0; st >>= 1) {
            if (tid < st) red[tid] += red[tid+st];
            __syncthreads();
        }
        if (tid == 0) logits[o] = red[0] + fb[o];
        __syncthreads();
    }
    if (tid == 0) {
        float mx = logits[0];
        for (int o = 1; o < OUTx; ++o) mx = fmaxf(mx, logits[o]);
        float dd = 0.0f; float e[OUTx];
        for (int o = 0; o < OUTx; ++o) { e[o] = expf(logits[o]-mx); dd += e[o]; }
        float inv = 1.0f/dd;
        for (int o = 0; o < OUTx; ++o) out[(size_t)b*OUTx + o] = e[o]*inv;
    }
}

// ---------------------------------------------------------------------------
static inline size_t alignup(size_t b) { return (b + 255) & ~(size_t)255; }

extern "C" void kernel_launch(void* const* d_in, const int* in_sizes, int n_in,
                              void* d_out, int out_size, void* d_ws, size_t ws_size,
                              hipStream_t stream)
{
    const float* x   = (const float*)d_in[0];
    // d_in[1] = unif -- dead
    const float* z   = (const float*)d_in[2];
    const float* mg  = (const float*)d_in[3];
    const float* w1  = (const float*)d_in[4];
    const float* b1  = (const float*)d_in[5];
    const float* w2  = (const float*)d_in[6];
    const float* b2  = (const float*)d_in[7];
    const float* c1  = (const float*)d_in[8];
    const float* c2  = (const float*)d_in[9];
    const float* fw  = (const float*)d_in[10];
    const float* fbv = (const float*)d_in[11];
    float* out = (float*)d_out;
    float* flp = out + (size_t)Bx*OUTx;
    (void)in_sizes; (void)n_in; (void)out_size;

    char* ws = (char*)d_ws;
    size_t off = 0;
    auto alloc = [&](size_t bytes) -> char* {
        char* p = ws + off; off += alignup(bytes); return p;
    };
    float*  feat = (float*)alloc((size_t)Bx*Nx*3*4);
    f32x4*  locp = (f32x4*)alloc((size_t)Bx*Nx*16);       // (lx,ly,hx,cn) per point
    uchar*  c1q  = (uchar*)alloc((size_t)SIGx*Nx);
    uchar*  c2q  = (uchar*)alloc((size_t)SIGx*Nx);
    uchar*  w2tq = (uchar*)alloc((size_t)HIDx*HIDx);
    uchar*  t1   = (uchar*)alloc((size_t)Bx*SIGx*HIDx);   // fp8 t
    uchar*  t2   = (uchar*)alloc((size_t)Bx*SIGx*HIDx);
    float*  m1   = (float*)alloc((size_t)SIGx*HIDx*4);
    float*  d1   = (float*)alloc((size_t)SIGx*HIDx*4);
    float*  m2   = (float*)alloc((size_t)SIGx*HIDx*4);
    float*  d2   = (float*)alloc((size_t)SIGx*HIDx*4);
    float*  sig  = (float*)alloc((size_t)Bx*SIGx*4);
    size_t fixed = off;

    int BC = 1;
    for (int c = Bx; c >= 1; c >>= 1) {
        size_t need = fixed + 2*alignup((size_t)c*HIDx*Nx);
        if (need <= ws_size) { BC = c; break; }
    }
    uchar* P1   = (uchar*)alloc((size_t)BC*HIDx*Nx);     // h2q
    uchar* P2   = (uchar*)alloc((size_t)BC*HIDx*Nx);     // s1q / s2q

    hipLaunchKernelGGL(kA_sample, dim3(Bx), dim3(Nx), 0, stream, x, z, mg, feat, flp);
    hipLaunchKernelGGL(kPrep, dim3(512), dim3(256), 0, stream, c1, c2, w2, c1q, c2q, w2tq);

    const int nch = Bx / BC;
    for (int c = 0; c < nch; ++c) {
        int b0 = c * BC;
        const float* featL = feat + (size_t)b0*Nx*3;
        f32x4* locpL = locp + (size_t)b0*Nx;
        uchar* t1L = t1 + (size_t)b0*SIGx*HIDx;
        uchar* t2L = t2 + (size_t)b0*SIGx*HIDx;
        // rank-3 pass-1 -> s1q; also emits locp (adj not materialized)
        hipLaunchKernelGGL(kFuse1, dim3(BC), dim3(512), 0, stream,
                           featL, w1, b1, locpL, P2);
        // t1 = (1/16) * c1q @ s1q -> fp8
        hipLaunchKernelGGL((kGstdQ<512,256,false>), dim3(BC, 4), dim3(256), 0, stream,
                           c1q, P2, t1L, 0.0625f);
        // h2q = (1/16) * w2tq @ s1q^T-staged -> fp8
        hipLaunchKernelGGL((kGstdQ<256,512,true>), dim3(BC, 8), dim3(256), 0, stream,
                           w2tq, P2, P1, 0.0625f);
        // s2q = 0.25 * relu(h2q @ adj + b2) -> fp8 ; adj recomputed (rt-merged)
        hipLaunchKernelGGL(kGemmAdjM, dim3(BC, 4), dim3(256), 0, stream,
                           P1, locpL, b2, P2);
        // t2 = 0.25 * c2q @ s2q  (16 * 1/4 undone) -> fp8
        hipLaunchKernelGGL((kGstdQ<512,256,false>), dim3(BC, 4), dim3(256), 0, stream,
                           c2q, P2, t2L, 0.25f);
    }

    hipLaunchKernelGGL(kF1q, dim3(SIGx), dim3(512), 0, stream,
                       t1, t2, m1, d1, m2, d2);
    hipLaunchKernelGGL(kF2q, dim3(SIGx/4, Bx), dim3(256), 0, stream,
                       t1, t2, m1, d1, m2, d2, sig);
    hipLaunchKernelGGL(kG_out, dim3(Bx), dim3(256), 0, stream, sig, fw, fbv, out);
}

// Round 3
// 292.503 us; speedup vs baseline: 1.2113x; 1.2113x over previous
//
#include <hip/hip_runtime.h>
#include <hip/hip_bf16.h>
#include <math.h>

#define Bx   256
#define Nx   512
#define SIGx 256
#define HIDx 256
#define OUTx 10
#define Hx   256

typedef __attribute__((ext_vector_type(4))) float f32x4;
typedef long fp8x8;          // 8 fp8 bytes = 2 VGPRs (MFMA A/B operand)
typedef unsigned char uchar;

__device__ inline uchar f2fp8(float v) {
    int r = __builtin_amdgcn_cvt_pk_fp8_f32(v, 0.0f, 0, false);
    return (uchar)(r & 0xff);
}
__device__ inline uint pk4fp8(float a0, float a1, float a2, float a3) {
    int r = __builtin_amdgcn_cvt_pk_fp8_f32(a0, a1, 0, false);
    r = __builtin_amdgcn_cvt_pk_fp8_f32(a2, a3, r, true);
    return (uint)r;
}

// async global->LDS, 16B per lane; lds dest = wave-uniform base + lane*16
__device__ inline void gload_lds16(const uchar* g, uchar* l) {
    __builtin_amdgcn_global_load_lds(
        (const __attribute__((address_space(1))) uint*)g,
        (__attribute__((address_space(3))) uint*)l, 16, 0, 0);
}
// swizzled LDS fragment address: 64B rows, 16B-unit XOR swizzle
__device__ inline const uchar* laddr(const uchar* base, int row, int kb) {
    int ps = (kb >> 4) ^ ((row >> 1) & 3) ^ ((row >> 4) & 3);
    return base + row*64 + ps*16 + (kb & 15);
}

// ---------------------------------------------------------------------------
// Kernel A: sampling stage (mixture fields constant over m => unif dead).
// ---------------------------------------------------------------------------
__global__ __launch_bounds__(512) void kA_sample(
    const float* __restrict__ x, const float* __restrict__ z,
    const float* __restrict__ mg, float* __restrict__ feat,
    float* __restrict__ flp)
{
    int b = blockIdx.x;
    int n = threadIdx.x;
    int g = n >> 5;
    float mux = mg[g*6+1];
    float muy = mg[g*6+2];
    float sxv = expf(mg[g*6+3]);
    float syv = expf(mg[g*6+4]);
    float rho = tanhf(mg[g*6+5]);
    float z1 = z[((size_t)b*Nx + n)*2 + 0];
    float z2 = z[((size_t)b*Nx + n)*2 + 1];
    float omr2 = 1.0f - rho*rho;
    float xs = mux + sxv*z1;
    float ys = muy + syv*(rho*z1 + sqrtf(omr2)*z2);
    float dx = xs - mux, dy = ys - muy;
    float quad = (dx*dx/(sxv*sxv) - 2.0f*rho*dx*dy/(sxv*syv) + dy*dy/(syv*syv)) / omr2;
    float logprob = -1.8378770664093453f - logf(sxv*syv) - 0.5f*logf(omr2) - 0.5f*quad;
    float lx = tanhf(xs), ly = tanhf(ys);
    int px = (int)truncf(0.5f*(lx+1.0f)*(float)Hx - 0.1f);
    int py = (int)truncf(0.5f*(ly+1.0f)*(float)Hx - 0.1f);
    px = px < 0 ? 0 : (px > Hx-1 ? Hx-1 : px);
    py = py < 0 ? 0 : (py > Hx-1 ? Hx-1 : py);
    float pv = x[(size_t)b*Hx*Hx + (size_t)px*Hx + py];
    size_t fo = ((size_t)b*Nx + n)*3;
    feat[fo+0] = pv; feat[fo+1] = lx; feat[fo+2] = ly;

    __shared__ float red[512];
    red[n] = logprob;
    __syncthreads();
    for (int st = 256; st > 0; st >>= 1) {
        if (n < st) red[n] += red[n+st];
        __syncthreads();
    }
    if (n == 0) flp[b] = red[0];
}

// ---------------------------------------------------------------------------
// Prep: c1,c2 -> fp8 (x16 scale); w2 -> w2t fp8 (x16, transposed).
// ---------------------------------------------------------------------------
__global__ __launch_bounds__(256) void kPrep(
    const float* __restrict__ c1, const float* __restrict__ c2,
    const float* __restrict__ w2,
    uchar* __restrict__ c1q, uchar* __restrict__ c2q, uchar* __restrict__ w2tq)
{
    int idx = blockIdx.x*256 + threadIdx.x;
    if (idx < SIGx*Nx) {
        c1q[idx] = f2fp8(16.0f * c1[idx]);
        c2q[idx] = f2fp8(16.0f * c2[idx]);
    }
    if (idx < HIDx*HIDx) {
        int i = idx >> 8, j = idx & 255;
        w2tq[idx] = f2fp8(16.0f * w2[j*HIDx + i]);
    }
}

// ===========================================================================
// kFuse1: per b -- generate adj (fp8, materialized), accumulate
// G[c][n] = sum_m featT[c][m]*adj[m][n] fp32, rank-3 epilogue
// s1t[h][n] = relu(w1[.][h].G + b1[h]) -> fp8.   (round-0 form)
// ===========================================================================
__global__ __launch_bounds__(512) void kFuse1(
    const float* __restrict__ featL, const float* __restrict__ w1,
    const float* __restrict__ b1,
    uchar* __restrict__ adjAll, uchar* __restrict__ s1tAll)
{
    int b = blockIdx.x;
    const float* fb = featL + (size_t)b*Nx*3;
    uchar* adj = adjAll + (size_t)b*Nx*Nx;
    uchar* s1t = s1tAll + (size_t)b*HIDx*Nx;

    __shared__ float fpv[Nx], flx[Nx], fly[Nx], fH[Nx];
    __shared__ float w1s[3*HIDx], b1s[HIDx];
    __shared__ float Gp[4][3][Nx];

    int t = threadIdx.x;
    {
        float pv = fb[t*3+0], lx = fb[t*3+1], ly = fb[t*3+2];
        fpv[t] = pv; flx[t] = lx; fly[t] = ly;
        fH[t] = fmaf(0.5f*lx, lx, fmaf(0.5f*ly, ly, 1.0f));
    }
    for (int i = t; i < 3*HIDx; i += 512) w1s[i] = w1[i];
    if (t < HIDx) b1s[t] = b1[t];
    __syncthreads();

    int tq = t & 127;          // column-quad index: n = 4*tq .. 4*tq+3
    int mc = t >> 7;           // m-chunk 0..3 (128 m each)
    int n4 = tq*4;

    float xn[4], yn[4], cn[4];
    #pragma unroll
    for (int e = 0; e < 4; ++e) {
        xn[e] = flx[n4+e]; yn[e] = fly[n4+e];
        cn[e] = fmaf(0.5f*xn[e], xn[e], 0.5f*yn[e]*yn[e]);
    }
    float G0[4] = {}, G1[4] = {}, G2[4] = {};

    int m0 = mc*128;
    #pragma unroll 4
    for (int mm = 0; mm < 128; ++mm) {
        int m = m0 + mm;
        float hx = fH[m], fx = flx[m], fy = fly[m];
        float a[4];
        #pragma unroll
        for (int e = 0; e < 4; ++e) {
            float s = fmaf(-yn[e], fy, fmaf(-xn[e], fx, hx + cn[e]));
            a[e] = __builtin_amdgcn_rcpf(s);
            G0[e] = fmaf(a[e], fpv[m], G0[e]);
            G1[e] = fmaf(a[e], fx, G1[e]);
            G2[e] = fmaf(a[e], fy, G2[e]);
        }
        *(uint*)(adj + (size_t)m*Nx + n4) = pk4fp8(a[0], a[1], a[2], a[3]);
    }

    *(f32x4*)&Gp[mc][0][n4] = (f32x4){G0[0],G0[1],G0[2],G0[3]};
    *(f32x4*)&Gp[mc][1][n4] = (f32x4){G1[0],G1[1],G1[2],G1[3]};
    *(f32x4*)&Gp[mc][2][n4] = (f32x4){G2[0],G2[1],G2[2],G2[3]};
    __syncthreads();

    f32x4 T0 = {}, T1 = {}, T2 = {};
    #pragma unroll
    for (int j = 0; j < 4; ++j) {
        T0 += *(const f32x4*)&Gp[j][0][n4];
        T1 += *(const f32x4*)&Gp[j][1][n4];
        T2 += *(const f32x4*)&Gp[j][2][n4];
    }

    int hc = mc;
    #pragma unroll 4
    for (int hh = 0; hh < 64; ++hh) {
        int h = hc*64 + hh;
        float w0 = w1s[h], wA = w1s[HIDx+h], wB = w1s[2*HIDx+h], bb = b1s[h];
        float v0 = fminf(fmaxf(fmaf(T0.x,w0, fmaf(T1.x,wA, fmaf(T2.x,wB, bb))), 0.0f), 448.0f);
        float v1 = fminf(fmaxf(fmaf(T0.y,w0, fmaf(T1.y,wA, fmaf(T2.y,wB, bb))), 0.0f), 448.0f);
        float v2 = fminf(fmaxf(fmaf(T0.z,w0, fmaf(T1.z,wA, fmaf(T2.z,wB, bb))), 0.0f), 448.0f);
        float v3 = fminf(fmaxf(fmaf(T0.w,w0, fmaf(T1.w,wA, fmaf(T2.w,wB, bb))), 0.0f), 448.0f);
        *(uint*)(s1t + (size_t)h*Nx + n4) = pk4fp8(v0, v1, v2, v3);
    }
}

// ===========================================================================
// kGemmAdjP: s2t[h][n] = 0.25*relu(sum_m h2t[h][m]*adj[m][n]+b2[h]).
// 2-PHASE: double-buffered LDS; next tile's global_load_lds issued BEFORE
// the MFMAs; ONE vmcnt-drain+barrier per K-step (T3-lite). Pure async
// staging -> no mid-step vmcnt drain. Math identical to round-0 kGemmAdjQ.
// ===========================================================================
__global__ __launch_bounds__(256) void kGemmAdjP(
    const uchar* __restrict__ Aall, const uchar* __restrict__ adjAll,
    const float* __restrict__ bias, uchar* __restrict__ outAll)
{
    int b    = blockIdx.x;
    int tile = blockIdx.y;
    int rt = tile >> 2;
    int ct = tile & 3;
    const uchar* A = Aall + (size_t)b*HIDx*Nx;
    const uchar* Badj = adjAll + (size_t)b*Nx*Nx;
    uchar* outp = outAll + (size_t)b*HIDx*Nx;

    __shared__ __align__(16) uchar Als[2][128*64];
    __shared__ __align__(16) uchar Bls[2][128*64];
    int t = threadIdx.x;
    int lane = t & 63, wave = t >> 6;
    int wr = wave >> 1, wc = wave & 1;
    int q = lane >> 4, c16 = lane & 15;
    int r0 = rt*128, n0 = ct*128;
    int lrow = lane >> 2;      // row-within-chunk for staging
    int pu   = lane & 3;       // 16B-unit within row
    f32x4 acc[4][4] = {};

    auto stage = [&](int buf, int kkv) {
        #pragma unroll
        for (int r = 0; r < 2; ++r) {
            int chunk = wave*2 + r;
            int row = chunk*16 + lrow;
            int sl = pu ^ ((row>>1)&3) ^ ((row>>4)&3);
            gload_lds16(A + (size_t)(r0+row)*Nx + kkv + sl*16, Als[buf] + chunk*1024);
            gload_lds16(Badj + (size_t)(n0+row)*Nx + kkv + sl*16, Bls[buf] + chunk*1024);
        }
    };

    stage(0, 0);
    __syncthreads();           // drains vmcnt; buf0 ready
    int cur = 0;
    for (int kk = 0; kk < Nx; kk += 64) {
        int nxt = cur ^ 1;
        if (kk + 64 < Nx) stage(nxt, kk + 64);   // loads fly over the MFMAs
        const uchar* Ac = Als[cur];
        const uchar* Bc = Bls[cur];
        #pragma unroll
        for (int ks = 0; ks < 64; ks += 32) {
            fp8x8 af[4], bfr[4];
            #pragma unroll
            for (int i = 0; i < 4; ++i)
                af[i] = *(const fp8x8*)laddr(Ac, wr*64 + i*16 + c16, ks + q*8);
            #pragma unroll
            for (int j = 0; j < 4; ++j)
                bfr[j] = *(const fp8x8*)laddr(Bc, wc*64 + j*16 + c16, ks + q*8);
            #pragma unroll
            for (int i = 0; i < 4; ++i)
                #pragma unroll
                for (int j = 0; j < 4; ++j)
                    acc[i][j] = __builtin_amdgcn_mfma_f32_16x16x32_fp8_fp8(af[i], bfr[j], acc[i][j], 0, 0, 0);
        }
        __syncthreads();       // single drain+barrier per K-step
        cur = nxt;
    }
    #pragma unroll
    for (int i = 0; i < 4; ++i) {
        int rowb = r0 + wr*64 + i*16 + q*4;
        #pragma unroll
        for (int j = 0; j < 4; ++j) {
            int col = n0 + wc*64 + j*16 + c16;
            #pragma unroll
            for (int r = 0; r < 4; ++r) {
                float v = fmaxf(acc[i][j][r] + bias[rowb + r], 0.0f) * 0.25f;
                outp[(size_t)(rowb + r)*Nx + col] = f2fp8(fminf(v, 448.0f));
            }
        }
    }
}

// ---------------------------------------------------------------------------
// kGstdP: C[row][col] = oscale * sum_k A[row][k]*B[k][col], fp8 in/out.
// 2-PHASE double-buffered. A (and non-TRB B) async-staged; TRB B uses the
// T14 split: global loads issued before the MFMAs, transpose ds_write after.
// ---------------------------------------------------------------------------
template<int K, int NC, bool TRB>
__global__ __launch_bounds__(256) void kGstdP(
    const uchar* __restrict__ Ash, const uchar* __restrict__ Ball,
    uchar* __restrict__ outAll, float oscale)
{
    constexpr int CT = NC / 128;
    int b    = blockIdx.x;
    int tile = blockIdx.y;
    int rt = tile / CT;
    int ct = tile % CT;
    const uchar* B = Ball + (size_t)b*HIDx*Nx;
    uchar* outp = outAll + (size_t)b*HIDx*NC;

    __shared__ __align__(16) uchar Als[2][128*64];
    __shared__ __align__(16) uchar Bls[2][128*64];
    int t = threadIdx.x;
    int lane = t & 63, wave = t >> 6;
    int wr = wave >> 1, wc = wave & 1;
    int q = lane >> 4, c16 = lane & 15;
    int r0 = rt*128, n0 = ct*128;
    int lrow = lane >> 2;
    int pu   = lane & 3;
    int pi  = t & 31;          // TRB: k-pair within 64-k tile
    int nc8 = t >> 5;          // TRB: 8 col-groups of 16
    f32x4 acc[4][4] = {};

    auto stageAsync = [&](int buf, int kkv) {
        #pragma unroll
        for (int r = 0; r < 2; ++r) {
            int chunk = wave*2 + r;
            int row = chunk*16 + lrow;
            int sl = pu ^ ((row>>1)&3) ^ ((row>>4)&3);
            gload_lds16(Ash + (size_t)(r0+row)*K + kkv + sl*16, Als[buf] + chunk*1024);
            if (!TRB)
                gload_lds16(B + (size_t)(n0+row)*K + kkv + sl*16, Bls[buf] + chunk*1024);
        }
    };
    auto loadBT = [&](int kkv, float4& v0, float4& v1) {
        int hk = kkv + 2*pi;
        const uchar* g0 = B + (size_t)hk*NC + n0 + nc8*16;
        v0 = *(const float4*)g0;
        v1 = *(const float4*)(g0 + NC);
    };
    auto writeBT = [&](int buf, const float4& v0, const float4& v1) {
        const uchar* pa = (const uchar*)&v0;
        const uchar* qa = (const uchar*)&v1;
        int kb = 2*pi;
        int s  = kb >> 4;
        #pragma unroll
        for (int e = 0; e < 16; ++e) {
            int row = nc8*16 + e;
            int ps = s ^ ((row>>1)&3) ^ ((row>>4)&3);
            *(ushort*)(Bls[buf] + row*64 + ps*16 + (kb & 15)) =
                (ushort)pa[e] | ((ushort)qa[e] << 8);
        }
    };

    float4 bv0, bv1;
    stageAsync(0, 0);
    if (TRB) { loadBT(0, bv0, bv1); writeBT(0, bv0, bv1); }
    __syncthreads();
    int cur = 0;
    for (int kk = 0; kk < K; kk += 64) {
        int nxt = cur ^ 1;
        bool more = (kk + 64) < K;
        if (more) {
            stageAsync(nxt, kk + 64);
            if (TRB) loadBT(kk + 64, bv0, bv1);   // regs; written after MFMAs
        }
        const uchar* Ac = Als[cur];
        const uchar* Bc = Bls[cur];
        #pragma unroll
        for (int ks = 0; ks < 64; ks += 32) {
            fp8x8 af[4], bfr[4];
            #pragma unroll
            for (int i = 0; i < 4; ++i)
                af[i] = *(const fp8x8*)laddr(Ac, wr*64 + i*16 + c16, ks + q*8);
            #pragma unroll
            for (int j = 0; j < 4; ++j)
                bfr[j] = *(const fp8x8*)laddr(Bc, wc*64 + j*16 + c16, ks + q*8);
            #pragma unroll
            for (int i = 0; i < 4; ++i)
                #pragma unroll
                for (int j = 0; j < 4; ++j)
                    acc[i][j] = __builtin_amdgcn_mfma_f32_16x16x32_fp8_fp8(af[i], bfr[j], acc[i][j], 0, 0, 0);
        }
        if (more && TRB) writeBT(nxt, bv0, bv1);
        __syncthreads();
        cur = nxt;
    }
    #pragma unroll
    for (int i = 0; i < 4; ++i) {
        int rowb = r0 + wr*64 + i*16 + q*4;
        #pragma unroll
        for (int j = 0; j < 4; ++j) {
            int col = n0 + wc*64 + j*16 + c16;
            #pragma unroll
            for (int r = 0; r < 4; ++r) {
                float v = acc[i][j][r] * oscale;
                v = fminf(fmaxf(v, -448.0f), 448.0f);
                outp[(size_t)(rowb + r)*NC + col] = f2fp8(v);
            }
        }
    }
}

// ---------------------------------------------------------------------------
// F1: single-pass online softmax-over-b stats for fp8 t1,t2. m and 1/d out.
// ---------------------------------------------------------------------------
__global__ __launch_bounds__(512) void kF1q(
    const uchar* __restrict__ t1, const uchar* __restrict__ t2,
    float* __restrict__ m1, float* __restrict__ rd1,
    float* __restrict__ m2, float* __restrict__ rd2)
{
    int s = blockIdx.x;
    int t = threadIdx.x;
    int hq = t & 63;
    int bq = t >> 6;
    const size_t str = (size_t)SIGx*HIDx;
    size_t base = (size_t)(bq*32)*str + (size_t)s*HIDx + hq*4;

    float mv1[4], dv1[4], mv2[4], dv2[4];
    #pragma unroll
    for (int e = 0; e < 4; ++e) { mv1[e]=-3.0e38f; dv1[e]=0.0f; mv2[e]=-3.0e38f; dv2[e]=0.0f; }

    for (int i = 0; i < 32; ++i) {
        uint u1 = *(const uint*)(t1 + base + (size_t)i*str);
        uint u2 = *(const uint*)(t2 + base + (size_t)i*str);
        float v1[4], v2[4];
        v1[0] = __builtin_amdgcn_cvt_f32_fp8(u1, 0);
        v1[1] = __builtin_amdgcn_cvt_f32_fp8(u1, 1);
        v1[2] = __builtin_amdgcn_cvt_f32_fp8(u1, 2);
        v1[3] = __builtin_amdgcn_cvt_f32_fp8(u1, 3);
        v2[0] = __builtin_amdgcn_cvt_f32_fp8(u2, 0);
        v2[1] = __builtin_amdgcn_cvt_f32_fp8(u2, 1);
        v2[2] = __builtin_amdgcn_cvt_f32_fp8(u2, 2);
        v2[3] = __builtin_amdgcn_cvt_f32_fp8(u2, 3);
        #pragma unroll
        for (int e = 0; e < 4; ++e) {
            float mn;
            mn = fmaxf(mv1[e], v1[e]);
            dv1[e] = dv1[e]*__expf(mv1[e]-mn) + __expf(v1[e]-mn); mv1[e] = mn;
            mn = fmaxf(mv2[e], v2[e]);
            dv2[e] = dv2[e]*__expf(mv2[e]-mn) + __expf(v2[e]-mn); mv2[e] = mn;
        }
    }

    __shared__ float pm1[8][256], pd1[8][256], pm2[8][256], pd2[8][256];
    #pragma unroll
    for (int e = 0; e < 4; ++e) {
        pm1[bq][hq*4+e] = mv1[e]; pd1[bq][hq*4+e] = dv1[e];
        pm2[bq][hq*4+e] = mv2[e]; pd2[bq][hq*4+e] = dv2[e];
    }
    __syncthreads();

    if (t < 256) {
        int h = t;
        float m = -3.0e38f, d = 0.0f;
        #pragma unroll
        for (int j = 0; j < 8; ++j) {
            float mm = pm1[j][h], dd = pd1[j][h];
            float mn = fmaxf(m, mm);
            d = d*__expf(m-mn) + dd*__expf(mm-mn);
            m = mn;
        }
        size_t o = (size_t)s*HIDx + h;
        m1[o] = m; rd1[o] = 1.0f/d;
    } else {
        int h = t - 256;
        float m = -3.0e38f, d = 0.0f;
        #pragma unroll
        for (int j = 0; j < 8; ++j) {
            float mm = pm2[j][h], dd = pd2[j][h];
            float mn = fmaxf(m, mm);
            d = d*__expf(m-mn) + dd*__expf(mm-mn);
            m = mn;
        }
        size_t o = (size_t)s*HIDx + h;
        m2[o] = m; rd2[o] = 1.0f/d;
    }
}

// ---------------------------------------------------------------------------
// F2: sig[b,s] = sum_h exp(t1-m1)*rd1 + exp(t2-m2)*rd2 (fp8 t).
// ---------------------------------------------------------------------------
__global__ __launch_bounds__(256) void kF2q(
    const uchar* __restrict__ t1, const uchar* __restrict__ t2,
    const float* __restrict__ m1, const float* __restrict__ rd1,
    const float* __restrict__ m2, const float* __restrict__ rd2,
    float* __restrict__ sig)
{
    int b = blockIdx.y;
    int sq = threadIdx.x >> 6;
    int s = blockIdx.x*4 + sq;
    int hq = threadIdx.x & 63;
    size_t sh = (size_t)s*HIDx + hq*4;
    size_t tb = ((size_t)b*SIGx + s)*HIDx + hq*4;
    uint u1 = *(const uint*)(t1 + tb);
    uint u2 = *(const uint*)(t2 + tb);
    f32x4 a1 = *(const f32x4*)&m1[sh];
    f32x4 r1 = *(const f32x4*)&rd1[sh];
    f32x4 a2 = *(const f32x4*)&m2[sh];
    f32x4 r2 = *(const f32x4*)&rd2[sh];
    float v = 0.0f;
    v += __expf(__builtin_amdgcn_cvt_f32_fp8(u1,0) - a1.x) * r1.x;
    v += __expf(__builtin_amdgcn_cvt_f32_fp8(u1,1) - a1.y) * r1.y;
    v += __expf(__builtin_amdgcn_cvt_f32_fp8(u1,2) - a1.z) * r1.z;
    v += __expf(__builtin_amdgcn_cvt_f32_fp8(u1,3) - a1.w) * r1.w;
    v += __expf(__builtin_amdgcn_cvt_f32_fp8(u2,0) - a2.x) * r2.x;
    v += __expf(__builtin_amdgcn_cvt_f32_fp8(u2,1) - a2.y) * r2.y;
    v += __expf(__builtin_amdgcn_cvt_f32_fp8(u2,2) - a2.z) * r2.z;
    v += __expf(__builtin_amdgcn_cvt_f32_fp8(u2,3) - a2.w) * r2.w;

    __shared__ float red[256];
    red[threadIdx.x] = v;
    __syncthreads();
    for (int st = 32; st > 0; st >>= 1) {
        if (hq < st) red[threadIdx.x] += red[threadIdx.x + st];
        __syncthreads();
    }
    if (hq == 0) sig[(size_t)b*SIGx + s] = red[sq*64];
}

// ---------------------------------------------------------------------------
// G: out[b,:] = softmax(sig[b,:] @ fcf_w.T + fcf_b)
// ---------------------------------------------------------------------------
__global__ __launch_bounds__(256) void kG_out(
    const float* __restrict__ sig, const float* __restrict__ fw,
    const float* __restrict__ fb, float* __restrict__ out)
{
    int b = blockIdx.x;
    int tid = threadIdx.x;
    __shared__ float red[256];
    __shared__ float logits[OUTx];
    float sv = sig[(size_t)b*SIGx + tid];
    for (int o = 0; o < OUTx; ++o) {
        red[tid] = sv * fw[o*SIGx + tid];
        __syncthreads();
        for (int st = 128; st > 0; st >>= 1) {
            if (tid < st) red[tid] += red[tid+st];
            __syncthreads();
        }
        if (tid == 0) logits[o] = red[0] + fb[o];
        __syncthreads();
    }
    if (tid == 0) {
        float mx = logits[0];
        for (int o = 1; o < OUTx; ++o) mx = fmaxf(mx, logits[o]);
        float dd = 0.0f; float e[OUTx];
        for (int o = 0; o < OUTx; ++o) { e[o] = expf(logits[o]-mx); dd += e[o]; }
        float inv = 1.0f/dd;
        for (int o = 0; o < OUTx; ++o) out[(size_t)b*OUTx + o] = e[o]*inv;
    }
}

// ---------------------------------------------------------------------------
static inline size_t alignup(size_t b) { return (b + 255) & ~(size_t)255; }

extern "C" void kernel_launch(void* const* d_in, const int* in_sizes, int n_in,
                              void* d_out, int out_size, void* d_ws, size_t ws_size,
                              hipStream_t stream)
{
    const float* x   = (const float*)d_in[0];
    // d_in[1] = unif -- dead
    const float* z   = (const float*)d_in[2];
    const float* mg  = (const float*)d_in[3];
    const float* w1  = (const float*)d_in[4];
    const float* b1  = (const float*)d_in[5];
    const float* w2  = (const float*)d_in[6];
    const float* b2  = (const float*)d_in[7];
    const float* c1  = (const float*)d_in[8];
    const float* c2  = (const float*)d_in[9];
    const float* fw  = (const float*)d_in[10];
    const float* fbv = (const float*)d_in[11];
    float* out = (float*)d_out;
    float* flp = out + (size_t)Bx*OUTx;
    (void)in_sizes; (void)n_in; (void)out_size;

    char* ws = (char*)d_ws;
    size_t off = 0;
    auto alloc = [&](size_t bytes) -> char* {
        char* p = ws + off; off += alignup(bytes); return p;
    };
    float*  feat = (float*)alloc((size_t)Bx*Nx*3*4);
    uchar*  c1q  = (uchar*)alloc((size_t)SIGx*Nx);
    uchar*  c2q  = (uchar*)alloc((size_t)SIGx*Nx);
    uchar*  w2tq = (uchar*)alloc((size_t)HIDx*HIDx);
    uchar*  t1   = (uchar*)alloc((size_t)Bx*SIGx*HIDx);   // fp8 t
    uchar*  t2   = (uchar*)alloc((size_t)Bx*SIGx*HIDx);
    float*  m1   = (float*)alloc((size_t)SIGx*HIDx*4);
    float*  d1   = (float*)alloc((size_t)SIGx*HIDx*4);
    float*  m2   = (float*)alloc((size_t)SIGx*HIDx*4);
    float*  d2   = (float*)alloc((size_t)SIGx*HIDx*4);
    float*  sig  = (float*)alloc((size_t)Bx*SIGx*4);
    size_t fixed = off;

    int BC = 1;
    for (int c = Bx; c >= 1; c >>= 1) {
        size_t need = fixed + alignup((size_t)c*Nx*Nx)
                            + 2*alignup((size_t)c*HIDx*Nx);
        if (need <= ws_size) { BC = c; break; }
    }
    uchar* Padj = (uchar*)alloc((size_t)BC*Nx*Nx);       // adj fp8
    uchar* P1   = (uchar*)alloc((size_t)BC*HIDx*Nx);     // h2q
    uchar* P2   = (uchar*)alloc((size_t)BC*HIDx*Nx);     // s1q / s2q

    hipLaunchKernelGGL(kA_sample, dim3(Bx), dim3(Nx), 0, stream, x, z, mg, feat, flp);
    hipLaunchKernelGGL(kPrep, dim3(512), dim3(256), 0, stream, c1, c2, w2, c1q, c2q, w2tq);

    const int nch = Bx / BC;
    for (int c = 0; c < nch; ++c) {
        int b0 = c * BC;
        const float* featL = feat + (size_t)b0*Nx*3;
        uchar* t1L = t1 + (size_t)b0*SIGx*HIDx;
        uchar* t2L = t2 + (size_t)b0*SIGx*HIDx;
        // adj (fp8) + rank-3 pass-1 -> s1q
        hipLaunchKernelGGL(kFuse1, dim3(BC), dim3(512), 0, stream,
                           featL, w1, b1, Padj, P2);
        // t1 = (1/16) * c1q @ s1q -> fp8
        hipLaunchKernelGGL((kGstdP<512,256,false>), dim3(BC, 4), dim3(256), 0, stream,
                           c1q, P2, t1L, 0.0625f);
        // h2q = (1/16) * w2tq @ s1q^T-staged -> fp8
        hipLaunchKernelGGL((kGstdP<256,512,true>), dim3(BC, 8), dim3(256), 0, stream,
                           w2tq, P2, P1, 0.0625f);
        // s2q = 0.25 * relu(h2q @ adj + b2) -> fp8
        hipLaunchKernelGGL(kGemmAdjP, dim3(BC, 8), dim3(256), 0, stream, P1, Padj, b2, P2);
        // t2 = 0.25 * c2q @ s2q  (16 * 1/4 undone) -> fp8
        hipLaunchKernelGGL((kGstdP<512,256,false>), dim3(BC, 4), dim3(256), 0, stream,
                           c2q, P2, t2L, 0.25f);
    }

    hipLaunchKernelGGL(kF1q, dim3(SIGx), dim3(512), 0, stream,
                       t1, t2, m1, d1, m2, d2);
    hipLaunchKernelGGL(kF2q, dim3(SIGx/4, Bx), dim3(256), 0, stream,
                       t1, t2, m1, d1, m2, d2, sig);
    hipLaunchKernelGGL(kG_out, dim3(Bx), dim3(256), 0, stream, sig, fw, fbv, out);
}

// Round 4
// 290.563 us; speedup vs baseline: 1.2194x; 1.0067x over previous
//
#include <hip/hip_runtime.h>
#include <hip/hip_bf16.h>
#include <math.h>

#define Bx   256
#define Nx   512
#define SIGx 256
#define HIDx 256
#define OUTx 10
#define Hx   256

typedef __attribute__((ext_vector_type(4))) float f32x4;
typedef long fp8x8;          // 8 fp8 bytes = 2 VGPRs (MFMA A/B operand)
typedef unsigned char uchar;

#define WAITVM(N) asm volatile("s_waitcnt vmcnt(" #N ")" ::: "memory")
#define MEMFENCE() asm volatile("" ::: "memory")

__device__ inline uchar f2fp8(float v) {
    int r = __builtin_amdgcn_cvt_pk_fp8_f32(v, 0.0f, 0, false);
    return (uchar)(r & 0xff);
}
__device__ inline uint pk4fp8(float a0, float a1, float a2, float a3) {
    int r = __builtin_amdgcn_cvt_pk_fp8_f32(a0, a1, 0, false);
    r = __builtin_amdgcn_cvt_pk_fp8_f32(a2, a3, r, true);
    return (uint)r;
}

// async global->LDS, 16B per lane; lds dest = wave-uniform base + lane*16
__device__ inline void gload_lds16(const uchar* g, uchar* l) {
    __builtin_amdgcn_global_load_lds(
        (const __attribute__((address_space(1))) uint*)g,
        (__attribute__((address_space(3))) uint*)l, 16, 0, 0);
}
// swizzled LDS fragment address: 64B rows, 16B-unit XOR swizzle
__device__ inline const uchar* laddr(const uchar* base, int row, int kb) {
    int ps = (kb >> 4) ^ ((row >> 1) & 3) ^ ((row >> 4) & 3);
    return base + row*64 + ps*16 + (kb & 15);
}

// ---------------------------------------------------------------------------
// Kernel A: sampling stage (mixture fields constant over m => unif dead).
// ---------------------------------------------------------------------------
__global__ __launch_bounds__(512) void kA_sample(
    const float* __restrict__ x, const float* __restrict__ z,
    const float* __restrict__ mg, float* __restrict__ feat,
    float* __restrict__ flp)
{
    int b = blockIdx.x;
    int n = threadIdx.x;
    int g = n >> 5;
    float mux = mg[g*6+1];
    float muy = mg[g*6+2];
    float sxv = expf(mg[g*6+3]);
    float syv = expf(mg[g*6+4]);
    float rho = tanhf(mg[g*6+5]);
    float z1 = z[((size_t)b*Nx + n)*2 + 0];
    float z2 = z[((size_t)b*Nx + n)*2 + 1];
    float omr2 = 1.0f - rho*rho;
    float xs = mux + sxv*z1;
    float ys = muy + syv*(rho*z1 + sqrtf(omr2)*z2);
    float dx = xs - mux, dy = ys - muy;
    float quad = (dx*dx/(sxv*sxv) - 2.0f*rho*dx*dy/(sxv*syv) + dy*dy/(syv*syv)) / omr2;
    float logprob = -1.8378770664093453f - logf(sxv*syv) - 0.5f*logf(omr2) - 0.5f*quad;
    float lx = tanhf(xs), ly = tanhf(ys);
    int px = (int)truncf(0.5f*(lx+1.0f)*(float)Hx - 0.1f);
    int py = (int)truncf(0.5f*(ly+1.0f)*(float)Hx - 0.1f);
    px = px < 0 ? 0 : (px > Hx-1 ? Hx-1 : px);
    py = py < 0 ? 0 : (py > Hx-1 ? Hx-1 : py);
    float pv = x[(size_t)b*Hx*Hx + (size_t)px*Hx + py];
    size_t fo = ((size_t)b*Nx + n)*3;
    feat[fo+0] = pv; feat[fo+1] = lx; feat[fo+2] = ly;

    __shared__ float red[512];
    red[n] = logprob;
    __syncthreads();
    for (int st = 256; st > 0; st >>= 1) {
        if (n < st) red[n] += red[n+st];
        __syncthreads();
    }
    if (n == 0) flp[b] = red[0];
}

// ---------------------------------------------------------------------------
// Prep: c1,c2 -> fp8 (x16 scale); w2 -> w2t fp8 (x16, transposed).
// ---------------------------------------------------------------------------
__global__ __launch_bounds__(256) void kPrep(
    const float* __restrict__ c1, const float* __restrict__ c2,
    const float* __restrict__ w2,
    uchar* __restrict__ c1q, uchar* __restrict__ c2q, uchar* __restrict__ w2tq)
{
    int idx = blockIdx.x*256 + threadIdx.x;
    if (idx < SIGx*Nx) {
        c1q[idx] = f2fp8(16.0f * c1[idx]);
        c2q[idx] = f2fp8(16.0f * c2[idx]);
    }
    if (idx < HIDx*HIDx) {
        int i = idx >> 8, j = idx & 255;
        w2tq[idx] = f2fp8(16.0f * w2[j*HIDx + i]);
    }
}

// ===========================================================================
// kFuse1: per b -- generate adj (fp8, materialized), accumulate
// G[c][n] = sum_m featT[c][m]*adj[m][n] fp32, rank-3 epilogue
// s1t[h][n] = relu(w1[.][h].G + b1[h]) -> fp8.   (round-0 form)
// ===========================================================================
__global__ __launch_bounds__(512) void kFuse1(
    const float* __restrict__ featL, const float* __restrict__ w1,
    const float* __restrict__ b1,
    uchar* __restrict__ adjAll, uchar* __restrict__ s1tAll)
{
    int b = blockIdx.x;
    const float* fb = featL + (size_t)b*Nx*3;
    uchar* adj = adjAll + (size_t)b*Nx*Nx;
    uchar* s1t = s1tAll + (size_t)b*HIDx*Nx;

    __shared__ float fpv[Nx], flx[Nx], fly[Nx], fH[Nx];
    __shared__ float w1s[3*HIDx], b1s[HIDx];
    __shared__ float Gp[4][3][Nx];

    int t = threadIdx.x;
    {
        float pv = fb[t*3+0], lx = fb[t*3+1], ly = fb[t*3+2];
        fpv[t] = pv; flx[t] = lx; fly[t] = ly;
        fH[t] = fmaf(0.5f*lx, lx, fmaf(0.5f*ly, ly, 1.0f));
    }
    for (int i = t; i < 3*HIDx; i += 512) w1s[i] = w1[i];
    if (t < HIDx) b1s[t] = b1[t];
    __syncthreads();

    int tq = t & 127;          // column-quad index: n = 4*tq .. 4*tq+3
    int mc = t >> 7;           // m-chunk 0..3 (128 m each)
    int n4 = tq*4;

    float xn[4], yn[4], cn[4];
    #pragma unroll
    for (int e = 0; e < 4; ++e) {
        xn[e] = flx[n4+e]; yn[e] = fly[n4+e];
        cn[e] = fmaf(0.5f*xn[e], xn[e], 0.5f*yn[e]*yn[e]);
    }
    float G0[4] = {}, G1[4] = {}, G2[4] = {};

    int m0 = mc*128;
    #pragma unroll 4
    for (int mm = 0; mm < 128; ++mm) {
        int m = m0 + mm;
        float hx = fH[m], fx = flx[m], fy = fly[m];
        float a[4];
        #pragma unroll
        for (int e = 0; e < 4; ++e) {
            float s = fmaf(-yn[e], fy, fmaf(-xn[e], fx, hx + cn[e]));
            a[e] = __builtin_amdgcn_rcpf(s);
            G0[e] = fmaf(a[e], fpv[m], G0[e]);
            G1[e] = fmaf(a[e], fx, G1[e]);
            G2[e] = fmaf(a[e], fy, G2[e]);
        }
        *(uint*)(adj + (size_t)m*Nx + n4) = pk4fp8(a[0], a[1], a[2], a[3]);
    }

    *(f32x4*)&Gp[mc][0][n4] = (f32x4){G0[0],G0[1],G0[2],G0[3]};
    *(f32x4*)&Gp[mc][1][n4] = (f32x4){G1[0],G1[1],G1[2],G1[3]};
    *(f32x4*)&Gp[mc][2][n4] = (f32x4){G2[0],G2[1],G2[2],G2[3]};
    __syncthreads();

    f32x4 T0 = {}, T1 = {}, T2 = {};
    #pragma unroll
    for (int j = 0; j < 4; ++j) {
        T0 += *(const f32x4*)&Gp[j][0][n4];
        T1 += *(const f32x4*)&Gp[j][1][n4];
        T2 += *(const f32x4*)&Gp[j][2][n4];
    }

    int hc = mc;
    #pragma unroll 4
    for (int hh = 0; hh < 64; ++hh) {
        int h = hc*64 + hh;
        float w0 = w1s[h], wA = w1s[HIDx+h], wB = w1s[2*HIDx+h], bb = b1s[h];
        float v0 = fminf(fmaxf(fmaf(T0.x,w0, fmaf(T1.x,wA, fmaf(T2.x,wB, bb))), 0.0f), 448.0f);
        float v1 = fminf(fmaxf(fmaf(T0.y,w0, fmaf(T1.y,wA, fmaf(T2.y,wB, bb))), 0.0f), 448.0f);
        float v2 = fminf(fmaxf(fmaf(T0.z,w0, fmaf(T1.z,wA, fmaf(T2.z,wB, bb))), 0.0f), 448.0f);
        float v3 = fminf(fmaxf(fmaf(T0.w,w0, fmaf(T1.w,wA, fmaf(T2.w,wB, bb))), 0.0f), 448.0f);
        *(uint*)(s1t + (size_t)h*Nx + n4) = pk4fp8(v0, v1, v2, v3);
    }
}

// ===========================================================================
// kGemmAdjC: s2t[h][n] = 0.25*relu(sum_m h2t[h][m]*adj[m][n]+b2[h]).
// T4 COUNTED-VMCNT pipeline: 3 LDS buffers, 2-deep prefetch. Per K-step:
//   stage t_{i+2} -> s_waitcnt vmcnt(8) -> s_barrier -> MFMA(buf i%3)
//   -> s_barrier.  vmcnt never drains to 0 in steady state.
// Loads/tile/wave L=4; in-flight tiles=2 -> N=8 (T4 formula).
// ===========================================================================
__global__ __launch_bounds__(256) void kGemmAdjC(
    const uchar* __restrict__ Aall, const uchar* __restrict__ adjAll,
    const float* __restrict__ bias, uchar* __restrict__ outAll)
{
    int b    = blockIdx.x;
    int tile = blockIdx.y;
    int rt = tile >> 2;
    int ct = tile & 3;
    const uchar* A = Aall + (size_t)b*HIDx*Nx;
    const uchar* Badj = adjAll + (size_t)b*Nx*Nx;
    uchar* outp = outAll + (size_t)b*HIDx*Nx;

    __shared__ __align__(16) uchar Als[3][128*64];
    __shared__ __align__(16) uchar Bls[3][128*64];
    int t = threadIdx.x;
    int lane = t & 63, wave = t >> 6;
    int wr = wave >> 1, wc = wave & 1;
    int q = lane >> 4, c16 = lane & 15;
    int r0 = rt*128, n0 = ct*128;
    int lrow = lane >> 2;      // row-within-chunk for staging
    int pu   = lane & 3;       // 16B-unit within row
    f32x4 acc[4][4] = {};

    auto stage = [&](int buf, int kkv) {
        #pragma unroll
        for (int r = 0; r < 2; ++r) {
            int chunk = wave*2 + r;
            int row = chunk*16 + lrow;
            int sl = pu ^ ((row>>1)&3) ^ ((row>>4)&3);
            gload_lds16(A + (size_t)(r0+row)*Nx + kkv + sl*16, Als[buf] + chunk*1024);
            gload_lds16(Badj + (size_t)(n0+row)*Nx + kkv + sl*16, Bls[buf] + chunk*1024);
        }
    };

    const int nt = Nx/64;      // 8
    stage(0, 0);
    stage(1, 64);
    for (int i = 0; i < nt; ++i) {
        if (i < nt-2) { stage((i+2)%3, (i+2)*64); WAITVM(8); }
        else if (i == nt-2) WAITVM(4);
        else WAITVM(0);
        __builtin_amdgcn_s_barrier();
        MEMFENCE();                              // keep ds_reads after barrier
        const uchar* Ac = Als[i%3];
        const uchar* Bc = Bls[i%3];
        #pragma unroll
        for (int ks = 0; ks < 64; ks += 32) {
            fp8x8 af[4], bfr[4];
            #pragma unroll
            for (int i2 = 0; i2 < 4; ++i2)
                af[i2] = *(const fp8x8*)laddr(Ac, wr*64 + i2*16 + c16, ks + q*8);
            #pragma unroll
            for (int j = 0; j < 4; ++j)
                bfr[j] = *(const fp8x8*)laddr(Bc, wc*64 + j*16 + c16, ks + q*8);
            #pragma unroll
            for (int i2 = 0; i2 < 4; ++i2)
                #pragma unroll
                for (int j = 0; j < 4; ++j)
                    acc[i2][j] = __builtin_amdgcn_mfma_f32_16x16x32_fp8_fp8(af[i2], bfr[j], acc[i2][j], 0, 0, 0);
        }
        MEMFENCE();                              // reads stay before barrier
        __builtin_amdgcn_s_barrier();            // write-after-read protect
        MEMFENCE();                              // next stage stays after
    }
    #pragma unroll
    for (int i = 0; i < 4; ++i) {
        int rowb = r0 + wr*64 + i*16 + q*4;
        #pragma unroll
        for (int j = 0; j < 4; ++j) {
            int col = n0 + wc*64 + j*16 + c16;
            #pragma unroll
            for (int r = 0; r < 4; ++r) {
                float v = fmaxf(acc[i][j][r] + bias[rowb + r], 0.0f) * 0.25f;
                outp[(size_t)(rowb + r)*Nx + col] = f2fp8(fminf(v, 448.0f));
            }
        }
    }
}

// ---------------------------------------------------------------------------
// kGstdP: C[row][col] = oscale * sum_k A[row][k]*B[k][col], fp8 in/out.
// non-TRB: T4 counted-vmcnt 3-buffer pipeline (pure async staging).
// TRB: proven round-3 2-phase path (reg-staged B transpose), kept separate
// to isolate risk.
// ---------------------------------------------------------------------------
template<int K, int NC, bool TRB>
__global__ __launch_bounds__(256) void kGstdP(
    const uchar* __restrict__ Ash, const uchar* __restrict__ Ball,
    uchar* __restrict__ outAll, float oscale)
{
    constexpr int CT = NC / 128;
    constexpr int NBUF = TRB ? 2 : 3;
    int b    = blockIdx.x;
    int tile = blockIdx.y;
    int rt = tile / CT;
    int ct = tile % CT;
    const uchar* B = Ball + (size_t)b*HIDx*Nx;
    uchar* outp = outAll + (size_t)b*HIDx*NC;

    __shared__ __align__(16) uchar Als[NBUF][128*64];
    __shared__ __align__(16) uchar Bls[NBUF][128*64];
    int t = threadIdx.x;
    int lane = t & 63, wave = t >> 6;
    int wr = wave >> 1, wc = wave & 1;
    int q = lane >> 4, c16 = lane & 15;
    int r0 = rt*128, n0 = ct*128;
    int lrow = lane >> 2;
    int pu   = lane & 3;
    int pi  = t & 31;          // TRB: k-pair within 64-k tile
    int nc8 = t >> 5;          // TRB: 8 col-groups of 16
    f32x4 acc[4][4] = {};

    auto stageAsync = [&](int buf, int kkv) {
        #pragma unroll
        for (int r = 0; r < 2; ++r) {
            int chunk = wave*2 + r;
            int row = chunk*16 + lrow;
            int sl = pu ^ ((row>>1)&3) ^ ((row>>4)&3);
            gload_lds16(Ash + (size_t)(r0+row)*K + kkv + sl*16, Als[buf] + chunk*1024);
            if (!TRB)
                gload_lds16(B + (size_t)(n0+row)*K + kkv + sl*16, Bls[buf] + chunk*1024);
        }
    };
    auto mfmaStep = [&](int buf) {
        const uchar* Ac = Als[buf];
        const uchar* Bc = Bls[buf];
        #pragma unroll
        for (int ks = 0; ks < 64; ks += 32) {
            fp8x8 af[4], bfr[4];
            #pragma unroll
            for (int i = 0; i < 4; ++i)
                af[i] = *(const fp8x8*)laddr(Ac, wr*64 + i*16 + c16, ks + q*8);
            #pragma unroll
            for (int j = 0; j < 4; ++j)
                bfr[j] = *(const fp8x8*)laddr(Bc, wc*64 + j*16 + c16, ks + q*8);
            #pragma unroll
            for (int i = 0; i < 4; ++i)
                #pragma unroll
                for (int j = 0; j < 4; ++j)
                    acc[i][j] = __builtin_amdgcn_mfma_f32_16x16x32_fp8_fp8(af[i], bfr[j], acc[i][j], 0, 0, 0);
        }
    };

    if (!TRB) {
        const int nt = K/64;
        stageAsync(0, 0);
        stageAsync(1, 64);
        for (int i = 0; i < nt; ++i) {
            if (i < nt-2) { stageAsync((i+2)%3, (i+2)*64); WAITVM(8); }
            else if (i == nt-2) WAITVM(4);
            else WAITVM(0);
            __builtin_amdgcn_s_barrier();
            MEMFENCE();
            mfmaStep(i%3);
            MEMFENCE();
            __builtin_amdgcn_s_barrier();
            MEMFENCE();
        }
    } else {
        auto loadBT = [&](int kkv, float4& v0, float4& v1) {
            int hk = kkv + 2*pi;
            const uchar* g0 = B + (size_t)hk*NC + n0 + nc8*16;
            v0 = *(const float4*)g0;
            v1 = *(const float4*)(g0 + NC);
        };
        auto writeBT = [&](int buf, const float4& v0, const float4& v1) {
            const uchar* pa = (const uchar*)&v0;
            const uchar* qa = (const uchar*)&v1;
            int kb = 2*pi;
            int s  = kb >> 4;
            #pragma unroll
            for (int e = 0; e < 16; ++e) {
                int row = nc8*16 + e;
                int ps = s ^ ((row>>1)&3) ^ ((row>>4)&3);
                *(ushort*)(Bls[buf] + row*64 + ps*16 + (kb & 15)) =
                    (ushort)pa[e] | ((ushort)qa[e] << 8);
            }
        };
        float4 bv0, bv1;
        stageAsync(0, 0);
        loadBT(0, bv0, bv1); writeBT(0, bv0, bv1);
        __syncthreads();
        int cur = 0;
        for (int kk = 0; kk < K; kk += 64) {
            int nxt = cur ^ 1;
            bool more = (kk + 64) < K;
            if (more) {
                stageAsync(nxt, kk + 64);
                loadBT(kk + 64, bv0, bv1);   // regs; written after MFMAs
            }
            mfmaStep(cur);
            if (more) writeBT(nxt, bv0, bv1);
            __syncthreads();
            cur = nxt;
        }
    }
    #pragma unroll
    for (int i = 0; i < 4; ++i) {
        int rowb = r0 + wr*64 + i*16 + q*4;
        #pragma unroll
        for (int j = 0; j < 4; ++j) {
            int col = n0 + wc*64 + j*16 + c16;
            #pragma unroll
            for (int r = 0; r < 4; ++r) {
                float v = acc[i][j][r] * oscale;
                v = fminf(fmaxf(v, -448.0f), 448.0f);
                outp[(size_t)(rowb + r)*NC + col] = f2fp8(v);
            }
        }
    }
}

// ---------------------------------------------------------------------------
// F1: single-pass online softmax-over-b stats for fp8 t1,t2. m and 1/d out.
// ---------------------------------------------------------------------------
__global__ __launch_bounds__(512) void kF1q(
    const uchar* __restrict__ t1, const uchar* __restrict__ t2,
    float* __restrict__ m1, float* __restrict__ rd1,
    float* __restrict__ m2, float* __restrict__ rd2)
{
    int s = blockIdx.x;
    int t = threadIdx.x;
    int hq = t & 63;
    int bq = t >> 6;
    const size_t str = (size_t)SIGx*HIDx;
    size_t base = (size_t)(bq*32)*str + (size_t)s*HIDx + hq*4;

    float mv1[4], dv1[4], mv2[4], dv2[4];
    #pragma unroll
    for (int e = 0; e < 4; ++e) { mv1[e]=-3.0e38f; dv1[e]=0.0f; mv2[e]=-3.0e38f; dv2[e]=0.0f; }

    for (int i = 0; i < 32; ++i) {
        uint u1 = *(const uint*)(t1 + base + (size_t)i*str);
        uint u2 = *(const uint*)(t2 + base + (size_t)i*str);
        float v1[4], v2[4];
        v1[0] = __builtin_amdgcn_cvt_f32_fp8(u1, 0);
        v1[1] = __builtin_amdgcn_cvt_f32_fp8(u1, 1);
        v1[2] = __builtin_amdgcn_cvt_f32_fp8(u1, 2);
        v1[3] = __builtin_amdgcn_cvt_f32_fp8(u1, 3);
        v2[0] = __builtin_amdgcn_cvt_f32_fp8(u2, 0);
        v2[1] = __builtin_amdgcn_cvt_f32_fp8(u2, 1);
        v2[2] = __builtin_amdgcn_cvt_f32_fp8(u2, 2);
        v2[3] = __builtin_amdgcn_cvt_f32_fp8(u2, 3);
        #pragma unroll
        for (int e = 0; e < 4; ++e) {
            float mn;
            mn = fmaxf(mv1[e], v1[e]);
            dv1[e] = dv1[e]*__expf(mv1[e]-mn) + __expf(v1[e]-mn); mv1[e] = mn;
            mn = fmaxf(mv2[e], v2[e]);
            dv2[e] = dv2[e]*__expf(mv2[e]-mn) + __expf(v2[e]-mn); mv2[e] = mn;
        }
    }

    __shared__ float pm1[8][256], pd1[8][256], pm2[8][256], pd2[8][256];
    #pragma unroll
    for (int e = 0; e < 4; ++e) {
        pm1[bq][hq*4+e] = mv1[e]; pd1[bq][hq*4+e] = dv1[e];
        pm2[bq][hq*4+e] = mv2[e]; pd2[bq][hq*4+e] = dv2[e];
    }
    __syncthreads();

    if (t < 256) {
        int h = t;
        float m = -3.0e38f, d = 0.0f;
        #pragma unroll
        for (int j = 0; j < 8; ++j) {
            float mm = pm1[j][h], dd = pd1[j][h];
            float mn = fmaxf(m, mm);
            d = d*__expf(m-mn) + dd*__expf(mm-mn);
            m = mn;
        }
        size_t o = (size_t)s*HIDx + h;
        m1[o] = m; rd1[o] = 1.0f/d;
    } else {
        int h = t - 256;
        float m = -3.0e38f, d = 0.0f;
        #pragma unroll
        for (int j = 0; j < 8; ++j) {
            float mm = pm2[j][h], dd = pd2[j][h];
            float mn = fmaxf(m, mm);
            d = d*__expf(m-mn) + dd*__expf(mm-mn);
            m = mn;
        }
        size_t o = (size_t)s*HIDx + h;
        m2[o] = m; rd2[o] = 1.0f/d;
    }
}

// ---------------------------------------------------------------------------
// F2: sig[b,s] = sum_h exp(t1-m1)*rd1 + exp(t2-m2)*rd2 (fp8 t).
// ---------------------------------------------------------------------------
__global__ __launch_bounds__(256) void kF2q(
    const uchar* __restrict__ t1, const uchar* __restrict__ t2,
    const float* __restrict__ m1, const float* __restrict__ rd1,
    const float* __restrict__ m2, const float* __restrict__ rd2,
    float* __restrict__ sig)
{
    int b = blockIdx.y;
    int sq = threadIdx.x >> 6;
    int s = blockIdx.x*4 + sq;
    int hq = threadIdx.x & 63;
    size_t sh = (size_t)s*HIDx + hq*4;
    size_t tb = ((size_t)b*SIGx + s)*HIDx + hq*4;
    uint u1 = *(const uint*)(t1 + tb);
    uint u2 = *(const uint*)(t2 + tb);
    f32x4 a1 = *(const f32x4*)&m1[sh];
    f32x4 r1 = *(const f32x4*)&rd1[sh];
    f32x4 a2 = *(const f32x4*)&m2[sh];
    f32x4 r2 = *(const f32x4*)&rd2[sh];
    float v = 0.0f;
    v += __expf(__builtin_amdgcn_cvt_f32_fp8(u1,0) - a1.x) * r1.x;
    v += __expf(__builtin_amdgcn_cvt_f32_fp8(u1,1) - a1.y) * r1.y;
    v += __expf(__builtin_amdgcn_cvt_f32_fp8(u1,2) - a1.z) * r1.z;
    v += __expf(__builtin_amdgcn_cvt_f32_fp8(u1,3) - a1.w) * r1.w;
    v += __expf(__builtin_amdgcn_cvt_f32_fp8(u2,0) - a2.x) * r2.x;
    v += __expf(__builtin_amdgcn_cvt_f32_fp8(u2,1) - a2.y) * r2.y;
    v += __expf(__builtin_amdgcn_cvt_f32_fp8(u2,2) - a2.z) * r2.z;
    v += __expf(__builtin_amdgcn_cvt_f32_fp8(u2,3) - a2.w) * r2.w;

    __shared__ float red[256];
    red[threadIdx.x] = v;
    __syncthreads();
    for (int st = 32; st > 0; st >>= 1) {
        if (hq < st) red[threadIdx.x] += red[threadIdx.x + st];
        __syncthreads();
    }
    if (hq == 0) sig[(size_t)b*SIGx + s] = red[sq*64];
}

// ---------------------------------------------------------------------------
// G: out[b,:] = softmax(sig[b,:] @ fcf_w.T + fcf_b)
// ---------------------------------------------------------------------------
__global__ __launch_bounds__(256) void kG_out(
    const float* __restrict__ sig, const float* __restrict__ fw,
    const float* __restrict__ fb, float* __restrict__ out)
{
    int b = blockIdx.x;
    int tid = threadIdx.x;
    __shared__ float red[256];
    __shared__ float logits[OUTx];
    float sv = sig[(size_t)b*SIGx + tid];
    for (int o = 0; o < OUTx; ++o) {
        red[tid] = sv * fw[o*SIGx + tid];
        __syncthreads();
        for (int st = 128; st > 0; st >>= 1) {
            if (tid < st) red[tid] += red[tid+st];
            __syncthreads();
        }
        if (tid == 0) logits[o] = red[0] + fb[o];
        __syncthreads();
    }
    if (tid == 0) {
        float mx = logits[0];
        for (int o = 1; o < OUTx; ++o) mx = fmaxf(mx, logits[o]);
        float dd = 0.0f; float e[OUTx];
        for (int o = 0; o < OUTx; ++o) { e[o] = expf(logits[o]-mx); dd += e[o]; }
        float inv = 1.0f/dd;
        for (int o = 0; o < OUTx; ++o) out[(size_t)b*OUTx + o] = e[o]*inv;
    }
}

// ---------------------------------------------------------------------------
static inline size_t alignup(size_t b) { return (b + 255) & ~(size_t)255; }

extern "C" void kernel_launch(void* const* d_in, const int* in_sizes, int n_in,
                              void* d_out, int out_size, void* d_ws, size_t ws_size,
                              hipStream_t stream)
{
    const float* x   = (const float*)d_in[0];
    // d_in[1] = unif -- dead
    const float* z   = (const float*)d_in[2];
    const float* mg  = (const float*)d_in[3];
    const float* w1  = (const float*)d_in[4];
    const float* b1  = (const float*)d_in[5];
    const float* w2  = (const float*)d_in[6];
    const float* b2  = (const float*)d_in[7];
    const float* c1  = (const float*)d_in[8];
    const float* c2  = (const float*)d_in[9];
    const float* fw  = (const float*)d_in[10];
    const float* fbv = (const float*)d_in[11];
    float* out = (float*)d_out;
    float* flp = out + (size_t)Bx*OUTx;
    (void)in_sizes; (void)n_in; (void)out_size;

    char* ws = (char*)d_ws;
    size_t off = 0;
    auto alloc = [&](size_t bytes) -> char* {
        char* p = ws + off; off += alignup(bytes); return p;
    };
    float*  feat = (float*)alloc((size_t)Bx*Nx*3*4);
    uchar*  c1q  = (uchar*)alloc((size_t)SIGx*Nx);
    uchar*  c2q  = (uchar*)alloc((size_t)SIGx*Nx);
    uchar*  w2tq = (uchar*)alloc((size_t)HIDx*HIDx);
    uchar*  t1   = (uchar*)alloc((size_t)Bx*SIGx*HIDx);   // fp8 t
    uchar*  t2   = (uchar*)alloc((size_t)Bx*SIGx*HIDx);
    float*  m1   = (float*)alloc((size_t)SIGx*HIDx*4);
    float*  d1   = (float*)alloc((size_t)SIGx*HIDx*4);
    float*  m2   = (float*)alloc((size_t)SIGx*HIDx*4);
    float*  d2   = (float*)alloc((size_t)SIGx*HIDx*4);
    float*  sig  = (float*)alloc((size_t)Bx*SIGx*4);
    size_t fixed = off;

    int BC = 1;
    for (int c = Bx; c >= 1; c >>= 1) {
        size_t need = fixed + alignup((size_t)c*Nx*Nx)
                            + 2*alignup((size_t)c*HIDx*Nx);
        if (need <= ws_size) { BC = c; break; }
    }
    uchar* Padj = (uchar*)alloc((size_t)BC*Nx*Nx);       // adj fp8
    uchar* P1   = (uchar*)alloc((size_t)BC*HIDx*Nx);     // h2q
    uchar* P2   = (uchar*)alloc((size_t)BC*HIDx*Nx);     // s1q / s2q

    hipLaunchKernelGGL(kA_sample, dim3(Bx), dim3(Nx), 0, stream, x, z, mg, feat, flp);
    hipLaunchKernelGGL(kPrep, dim3(512), dim3(256), 0, stream, c1, c2, w2, c1q, c2q, w2tq);

    const int nch = Bx / BC;
    for (int c = 0; c < nch; ++c) {
        int b0 = c * BC;
        const float* featL = feat + (size_t)b0*Nx*3;
        uchar* t1L = t1 + (size_t)b0*SIGx*HIDx;
        uchar* t2L = t2 + (size_t)b0*SIGx*HIDx;
        // adj (fp8) + rank-3 pass-1 -> s1q
        hipLaunchKernelGGL(kFuse1, dim3(BC), dim3(512), 0, stream,
                           featL, w1, b1, Padj, P2);
        // t1 = (1/16) * c1q @ s1q -> fp8
        hipLaunchKernelGGL((kGstdP<512,256,false>), dim3(BC, 4), dim3(256), 0, stream,
                           c1q, P2, t1L, 0.0625f);
        // h2q = (1/16) * w2tq @ s1q^T-staged -> fp8
        hipLaunchKernelGGL((kGstdP<256,512,true>), dim3(BC, 8), dim3(256), 0, stream,
                           w2tq, P2, P1, 0.0625f);
        // s2q = 0.25 * relu(h2q @ adj + b2) -> fp8 (counted-vmcnt pipeline)
        hipLaunchKernelGGL(kGemmAdjC, dim3(BC, 8), dim3(256), 0, stream, P1, Padj, b2, P2);
        // t2 = 0.25 * c2q @ s2q  (16 * 1/4 undone) -> fp8
        hipLaunchKernelGGL((kGstdP<512,256,false>), dim3(BC, 4), dim3(256), 0, stream,
                           c2q, P2, t2L, 0.25f);
    }

    hipLaunchKernelGGL(kF1q, dim3(SIGx), dim3(512), 0, stream,
                       t1, t2, m1, d1, m2, d2);
    hipLaunchKernelGGL(kF2q, dim3(SIGx/4, Bx), dim3(256), 0, stream,
                       t1, t2, m1, d1, m2, d2, sig);
    hipLaunchKernelGGL(kG_out, dim3(Bx), dim3(256), 0, stream, sig, fw, fbv, out);
}

// Round 5
// 289.237 us; speedup vs baseline: 1.2250x; 1.0046x over previous
//
#include <hip/hip_runtime.h>
#include <hip/hip_bf16.h>
#include <math.h>

#define Bx   256
#define Nx   512
#define SIGx 256
#define HIDx 256
#define OUTx 10
#define Hx   256

typedef __attribute__((ext_vector_type(4))) float f32x4;
typedef long fp8x8;          // 8 fp8 bytes = 2 VGPRs (MFMA A/B operand)
typedef unsigned char uchar;

#define WAITVM(N) asm volatile("s_waitcnt vmcnt(" #N ")" ::: "memory")
#define MEMFENCE() asm volatile("" ::: "memory")

__device__ inline uchar f2fp8(float v) {
    int r = __builtin_amdgcn_cvt_pk_fp8_f32(v, 0.0f, 0, false);
    return (uchar)(r & 0xff);
}
__device__ inline uint pk4fp8(float a0, float a1, float a2, float a3) {
    int r = __builtin_amdgcn_cvt_pk_fp8_f32(a0, a1, 0, false);
    r = __builtin_amdgcn_cvt_pk_fp8_f32(a2, a3, r, true);
    return (uint)r;
}

// async global->LDS, 16B per lane; lds dest = wave-uniform base + lane*16
__device__ inline void gload_lds16(const uchar* g, uchar* l) {
    __builtin_amdgcn_global_load_lds(
        (const __attribute__((address_space(1))) uint*)g,
        (__attribute__((address_space(3))) uint*)l, 16, 0, 0);
}
// swizzled LDS fragment address: 64B rows, 16B-unit XOR swizzle
__device__ inline const uchar* laddr(const uchar* base, int row, int kb) {
    int ps = (kb >> 4) ^ ((row >> 1) & 3) ^ ((row >> 4) & 3);
    return base + row*64 + ps*16 + (kb & 15);
}

// ---------------------------------------------------------------------------
// Kernel A: sampling stage (mixture fields constant over m => unif dead).
// ---------------------------------------------------------------------------
__global__ __launch_bounds__(512) void kA_sample(
    const float* __restrict__ x, const float* __restrict__ z,
    const float* __restrict__ mg, float* __restrict__ feat,
    float* __restrict__ flp)
{
    int b = blockIdx.x;
    int n = threadIdx.x;
    int g = n >> 5;
    float mux = mg[g*6+1];
    float muy = mg[g*6+2];
    float sxv = expf(mg[g*6+3]);
    float syv = expf(mg[g*6+4]);
    float rho = tanhf(mg[g*6+5]);
    float z1 = z[((size_t)b*Nx + n)*2 + 0];
    float z2 = z[((size_t)b*Nx + n)*2 + 1];
    float omr2 = 1.0f - rho*rho;
    float xs = mux + sxv*z1;
    float ys = muy + syv*(rho*z1 + sqrtf(omr2)*z2);
    float dx = xs - mux, dy = ys - muy;
    float quad = (dx*dx/(sxv*sxv) - 2.0f*rho*dx*dy/(sxv*syv) + dy*dy/(syv*syv)) / omr2;
    float logprob = -1.8378770664093453f - logf(sxv*syv) - 0.5f*logf(omr2) - 0.5f*quad;
    float lx = tanhf(xs), ly = tanhf(ys);
    int px = (int)truncf(0.5f*(lx+1.0f)*(float)Hx - 0.1f);
    int py = (int)truncf(0.5f*(ly+1.0f)*(float)Hx - 0.1f);
    px = px < 0 ? 0 : (px > Hx-1 ? Hx-1 : px);
    py = py < 0 ? 0 : (py > Hx-1 ? Hx-1 : py);
    float pv = x[(size_t)b*Hx*Hx + (size_t)px*Hx + py];
    size_t fo = ((size_t)b*Nx + n)*3;
    feat[fo+0] = pv; feat[fo+1] = lx; feat[fo+2] = ly;

    __shared__ float red[512];
    red[n] = logprob;
    __syncthreads();
    for (int st = 256; st > 0; st >>= 1) {
        if (n < st) red[n] += red[n+st];
        __syncthreads();
    }
    if (n == 0) flp[b] = red[0];
}

// ---------------------------------------------------------------------------
// Prep: c1,c2 -> fp8 (x16 scale); w2 -> w2t fp8 (x16, transposed).
// ---------------------------------------------------------------------------
__global__ __launch_bounds__(256) void kPrep(
    const float* __restrict__ c1, const float* __restrict__ c2,
    const float* __restrict__ w2,
    uchar* __restrict__ c1q, uchar* __restrict__ c2q, uchar* __restrict__ w2tq)
{
    int idx = blockIdx.x*256 + threadIdx.x;
    if (idx < SIGx*Nx) {
        c1q[idx] = f2fp8(16.0f * c1[idx]);
        c2q[idx] = f2fp8(16.0f * c2[idx]);
    }
    if (idx < HIDx*HIDx) {
        int i = idx >> 8, j = idx & 255;
        w2tq[idx] = f2fp8(16.0f * w2[j*HIDx + i]);
    }
}

// ===========================================================================
// kFuse1: per b -- generate adj (fp8, materialized), accumulate
// G[c][n] = sum_m featT[c][m]*adj[m][n] fp32, rank-3 epilogue
// s1t[h][n] = relu(w1[.][h].G + b1[h]) -> fp8.   (round-0 form)
// ===========================================================================
__global__ __launch_bounds__(512) void kFuse1(
    const float* __restrict__ featL, const float* __restrict__ w1,
    const float* __restrict__ b1,
    uchar* __restrict__ adjAll, uchar* __restrict__ s1tAll)
{
    int b = blockIdx.x;
    const float* fb = featL + (size_t)b*Nx*3;
    uchar* adj = adjAll + (size_t)b*Nx*Nx;
    uchar* s1t = s1tAll + (size_t)b*HIDx*Nx;

    __shared__ float fpv[Nx], flx[Nx], fly[Nx], fH[Nx];
    __shared__ float w1s[3*HIDx], b1s[HIDx];
    __shared__ float Gp[4][3][Nx];

    int t = threadIdx.x;
    {
        float pv = fb[t*3+0], lx = fb[t*3+1], ly = fb[t*3+2];
        fpv[t] = pv; flx[t] = lx; fly[t] = ly;
        fH[t] = fmaf(0.5f*lx, lx, fmaf(0.5f*ly, ly, 1.0f));
    }
    for (int i = t; i < 3*HIDx; i += 512) w1s[i] = w1[i];
    if (t < HIDx) b1s[t] = b1[t];
    __syncthreads();

    int tq = t & 127;          // column-quad index: n = 4*tq .. 4*tq+3
    int mc = t >> 7;           // m-chunk 0..3 (128 m each)
    int n4 = tq*4;

    float xn[4], yn[4], cn[4];
    #pragma unroll
    for (int e = 0; e < 4; ++e) {
        xn[e] = flx[n4+e]; yn[e] = fly[n4+e];
        cn[e] = fmaf(0.5f*xn[e], xn[e], 0.5f*yn[e]*yn[e]);
    }
    float G0[4] = {}, G1[4] = {}, G2[4] = {};

    int m0 = mc*128;
    #pragma unroll 4
    for (int mm = 0; mm < 128; ++mm) {
        int m = m0 + mm;
        float hx = fH[m], fx = flx[m], fy = fly[m];
        float a[4];
        #pragma unroll
        for (int e = 0; e < 4; ++e) {
            float s = fmaf(-yn[e], fy, fmaf(-xn[e], fx, hx + cn[e]));
            a[e] = __builtin_amdgcn_rcpf(s);
            G0[e] = fmaf(a[e], fpv[m], G0[e]);
            G1[e] = fmaf(a[e], fx, G1[e]);
            G2[e] = fmaf(a[e], fy, G2[e]);
        }
        *(uint*)(adj + (size_t)m*Nx + n4) = pk4fp8(a[0], a[1], a[2], a[3]);
    }

    *(f32x4*)&Gp[mc][0][n4] = (f32x4){G0[0],G0[1],G0[2],G0[3]};
    *(f32x4*)&Gp[mc][1][n4] = (f32x4){G1[0],G1[1],G1[2],G1[3]};
    *(f32x4*)&Gp[mc][2][n4] = (f32x4){G2[0],G2[1],G2[2],G2[3]};
    __syncthreads();

    f32x4 T0 = {}, T1 = {}, T2 = {};
    #pragma unroll
    for (int j = 0; j < 4; ++j) {
        T0 += *(const f32x4*)&Gp[j][0][n4];
        T1 += *(const f32x4*)&Gp[j][1][n4];
        T2 += *(const f32x4*)&Gp[j][2][n4];
    }

    int hc = mc;
    #pragma unroll 4
    for (int hh = 0; hh < 64; ++hh) {
        int h = hc*64 + hh;
        float w0 = w1s[h], wA = w1s[HIDx+h], wB = w1s[2*HIDx+h], bb = b1s[h];
        float v0 = fminf(fmaxf(fmaf(T0.x,w0, fmaf(T1.x,wA, fmaf(T2.x,wB, bb))), 0.0f), 448.0f);
        float v1 = fminf(fmaxf(fmaf(T0.y,w0, fmaf(T1.y,wA, fmaf(T2.y,wB, bb))), 0.0f), 448.0f);
        float v2 = fminf(fmaxf(fmaf(T0.z,w0, fmaf(T1.z,wA, fmaf(T2.z,wB, bb))), 0.0f), 448.0f);
        float v3 = fminf(fmaxf(fmaf(T0.w,w0, fmaf(T1.w,wA, fmaf(T2.w,wB, bb))), 0.0f), 448.0f);
        *(uint*)(s1t + (size_t)h*Nx + n4) = pk4fp8(v0, v1, v2, v3);
    }
}

// ===========================================================================
// kGemmAdj8: s2t[h][n] = 0.25*relu(sum_m h2t[h][m]*adj[m][n]+b2[h]).
// 8-WAVE occupancy version: 512 thr, wave-tile 64x32 -> acc[4][2] (32 AGPR,
// half of round-0) so ~2x waves/CU resident. 3-buffer counted-vmcnt
// pipeline (2 loads/thread/tile -> steady WAITVM(4)). Math bit-identical.
// ===========================================================================
__global__ __launch_bounds__(512, 4) void kGemmAdj8(
    const uchar* __restrict__ Aall, const uchar* __restrict__ adjAll,
    const float* __restrict__ bias, uchar* __restrict__ outAll)
{
    int b    = blockIdx.x;
    int tile = blockIdx.y;
    int rt = tile >> 2;
    int ct = tile & 3;
    const uchar* A = Aall + (size_t)b*HIDx*Nx;
    const uchar* Badj = adjAll + (size_t)b*Nx*Nx;
    uchar* outp = outAll + (size_t)b*HIDx*Nx;

    __shared__ __align__(16) uchar Als[3][128*64];
    __shared__ __align__(16) uchar Bls[3][128*64];
    int t = threadIdx.x;
    int lane = t & 63, wave = t >> 6;
    int wr = wave >> 2, wc = wave & 3;       // 2x4 wave grid, 64x32 each
    int q = lane >> 4, c16 = lane & 15;
    int r0 = rt*128, n0 = ct*128;
    int srow = wave*16 + (lane >> 2);        // staging row (one chunk/wave)
    int pu   = lane & 3;
    int sl   = pu ^ ((srow>>1)&3) ^ ((srow>>4)&3);
    f32x4 acc[4][2] = {};

    auto stage = [&](int buf, int kkv) {     // 2 loads per thread
        gload_lds16(A + (size_t)(r0+srow)*Nx + kkv + sl*16, Als[buf] + wave*1024);
        gload_lds16(Badj + (size_t)(n0+srow)*Nx + kkv + sl*16, Bls[buf] + wave*1024);
    };

    const int nt = Nx/64;      // 8
    stage(0, 0);
    stage(1, 64);
    for (int i = 0; i < nt; ++i) {
        if (i < nt-2) { stage((i+2)%3, (i+2)*64); WAITVM(4); }
        else if (i == nt-2) WAITVM(2);
        else WAITVM(0);
        __builtin_amdgcn_s_barrier();
        MEMFENCE();
        const uchar* Ac = Als[i%3];
        const uchar* Bc = Bls[i%3];
        #pragma unroll
        for (int ks = 0; ks < 64; ks += 32) {
            fp8x8 af[4], bfr[2];
            #pragma unroll
            for (int i2 = 0; i2 < 4; ++i2)
                af[i2] = *(const fp8x8*)laddr(Ac, wr*64 + i2*16 + c16, ks + q*8);
            #pragma unroll
            for (int j = 0; j < 2; ++j)
                bfr[j] = *(const fp8x8*)laddr(Bc, wc*32 + j*16 + c16, ks + q*8);
            #pragma unroll
            for (int i2 = 0; i2 < 4; ++i2)
                #pragma unroll
                for (int j = 0; j < 2; ++j)
                    acc[i2][j] = __builtin_amdgcn_mfma_f32_16x16x32_fp8_fp8(af[i2], bfr[j], acc[i2][j], 0, 0, 0);
        }
        MEMFENCE();
        __builtin_amdgcn_s_barrier();        // write-after-read protect
        MEMFENCE();
    }
    #pragma unroll
    for (int i = 0; i < 4; ++i) {
        int rowb = r0 + wr*64 + i*16 + q*4;
        #pragma unroll
        for (int j = 0; j < 2; ++j) {
            int col = n0 + wc*32 + j*16 + c16;
            #pragma unroll
            for (int r = 0; r < 4; ++r) {
                float v = fmaxf(acc[i][j][r] + bias[rowb + r], 0.0f) * 0.25f;
                outp[(size_t)(rowb + r)*Nx + col] = f2fp8(fminf(v, 448.0f));
            }
        }
    }
}

// ===========================================================================
// kGstd8: C[row][col] = oscale * sum_k A[row][k]*B[k][col]; K=512, NC=256.
// Same 8-wave / acc[4][2] / 3-buffer counted-vmcnt structure as kGemmAdj8.
// A = 128KB weight (L2-hot, shared across b); B row-stride 512.
// ===========================================================================
__global__ __launch_bounds__(512, 4) void kGstd8(
    const uchar* __restrict__ Ash, const uchar* __restrict__ Ball,
    uchar* __restrict__ outAll, float oscale)
{
    int b    = blockIdx.x;
    int tile = blockIdx.y;                   // 0..3
    int rt = tile >> 1;
    int ct = tile & 1;
    const uchar* B = Ball + (size_t)b*HIDx*Nx;
    uchar* outp = outAll + (size_t)b*HIDx*256;

    __shared__ __align__(16) uchar Als[3][128*64];
    __shared__ __align__(16) uchar Bls[3][128*64];
    int t = threadIdx.x;
    int lane = t & 63, wave = t >> 6;
    int wr = wave >> 2, wc = wave & 3;
    int q = lane >> 4, c16 = lane & 15;
    int r0 = rt*128, n0 = ct*128;
    int srow = wave*16 + (lane >> 2);
    int pu   = lane & 3;
    int sl   = pu ^ ((srow>>1)&3) ^ ((srow>>4)&3);
    f32x4 acc[4][2] = {};

    auto stage = [&](int buf, int kkv) {
        gload_lds16(Ash + (size_t)(r0+srow)*Nx + kkv + sl*16, Als[buf] + wave*1024);
        gload_lds16(B + (size_t)(n0+srow)*Nx + kkv + sl*16, Bls[buf] + wave*1024);
    };

    const int nt = Nx/64;      // 8
    stage(0, 0);
    stage(1, 64);
    for (int i = 0; i < nt; ++i) {
        if (i < nt-2) { stage((i+2)%3, (i+2)*64); WAITVM(4); }
        else if (i == nt-2) WAITVM(2);
        else WAITVM(0);
        __builtin_amdgcn_s_barrier();
        MEMFENCE();
        const uchar* Ac = Als[i%3];
        const uchar* Bc = Bls[i%3];
        #pragma unroll
        for (int ks = 0; ks < 64; ks += 32) {
            fp8x8 af[4], bfr[2];
            #pragma unroll
            for (int i2 = 0; i2 < 4; ++i2)
                af[i2] = *(const fp8x8*)laddr(Ac, wr*64 + i2*16 + c16, ks + q*8);
            #pragma unroll
            for (int j = 0; j < 2; ++j)
                bfr[j] = *(const fp8x8*)laddr(Bc, wc*32 + j*16 + c16, ks + q*8);
            #pragma unroll
            for (int i2 = 0; i2 < 4; ++i2)
                #pragma unroll
                for (int j = 0; j < 2; ++j)
                    acc[i2][j] = __builtin_amdgcn_mfma_f32_16x16x32_fp8_fp8(af[i2], bfr[j], acc[i2][j], 0, 0, 0);
        }
        MEMFENCE();
        __builtin_amdgcn_s_barrier();
        MEMFENCE();
    }
    #pragma unroll
    for (int i = 0; i < 4; ++i) {
        int rowb = r0 + wr*64 + i*16 + q*4;
        #pragma unroll
        for (int j = 0; j < 2; ++j) {
            int col = n0 + wc*32 + j*16 + c16;
            #pragma unroll
            for (int r = 0; r < 4; ++r) {
                float v = acc[i][j][r] * oscale;
                v = fminf(fmaxf(v, -448.0f), 448.0f);
                outp[(size_t)(rowb + r)*256 + col] = f2fp8(v);
            }
        }
    }
}

// ---------------------------------------------------------------------------
// kGstdP (TRB only): C = oscale * A @ B^T-staged, round-4 2-phase path.
// ---------------------------------------------------------------------------
template<int K, int NC, bool TRB>
__global__ __launch_bounds__(256) void kGstdP(
    const uchar* __restrict__ Ash, const uchar* __restrict__ Ball,
    uchar* __restrict__ outAll, float oscale)
{
    constexpr int CT = NC / 128;
    int b    = blockIdx.x;
    int tile = blockIdx.y;
    int rt = tile / CT;
    int ct = tile % CT;
    const uchar* B = Ball + (size_t)b*HIDx*Nx;
    uchar* outp = outAll + (size_t)b*HIDx*NC;

    __shared__ __align__(16) uchar Als[2][128*64];
    __shared__ __align__(16) uchar Bls[2][128*64];
    int t = threadIdx.x;
    int lane = t & 63, wave = t >> 6;
    int wr = wave >> 1, wc = wave & 1;
    int q = lane >> 4, c16 = lane & 15;
    int r0 = rt*128, n0 = ct*128;
    int lrow = lane >> 2;
    int pu   = lane & 3;
    int pi  = t & 31;          // TRB: k-pair within 64-k tile
    int nc8 = t >> 5;          // TRB: 8 col-groups of 16
    f32x4 acc[4][4] = {};

    auto stageAsync = [&](int buf, int kkv) {
        #pragma unroll
        for (int r = 0; r < 2; ++r) {
            int chunk = wave*2 + r;
            int row = chunk*16 + lrow;
            int sl = pu ^ ((row>>1)&3) ^ ((row>>4)&3);
            gload_lds16(Ash + (size_t)(r0+row)*K + kkv + sl*16, Als[buf] + chunk*1024);
            if (!TRB)
                gload_lds16(B + (size_t)(n0+row)*K + kkv + sl*16, Bls[buf] + chunk*1024);
        }
    };
    auto mfmaStep = [&](int buf) {
        const uchar* Ac = Als[buf];
        const uchar* Bc = Bls[buf];
        #pragma unroll
        for (int ks = 0; ks < 64; ks += 32) {
            fp8x8 af[4], bfr[4];
            #pragma unroll
            for (int i = 0; i < 4; ++i)
                af[i] = *(const fp8x8*)laddr(Ac, wr*64 + i*16 + c16, ks + q*8);
            #pragma unroll
            for (int j = 0; j < 4; ++j)
                bfr[j] = *(const fp8x8*)laddr(Bc, wc*64 + j*16 + c16, ks + q*8);
            #pragma unroll
            for (int i = 0; i < 4; ++i)
                #pragma unroll
                for (int j = 0; j < 4; ++j)
                    acc[i][j] = __builtin_amdgcn_mfma_f32_16x16x32_fp8_fp8(af[i], bfr[j], acc[i][j], 0, 0, 0);
        }
    };

    auto loadBT = [&](int kkv, float4& v0, float4& v1) {
        int hk = kkv + 2*pi;
        const uchar* g0 = B + (size_t)hk*NC + n0 + nc8*16;
        v0 = *(const float4*)g0;
        v1 = *(const float4*)(g0 + NC);
    };
    auto writeBT = [&](int buf, const float4& v0, const float4& v1) {
        const uchar* pa = (const uchar*)&v0;
        const uchar* qa = (const uchar*)&v1;
        int kb = 2*pi;
        int s  = kb >> 4;
        #pragma unroll
        for (int e = 0; e < 16; ++e) {
            int row = nc8*16 + e;
            int ps = s ^ ((row>>1)&3) ^ ((row>>4)&3);
            *(ushort*)(Bls[buf] + row*64 + ps*16 + (kb & 15)) =
                (ushort)pa[e] | ((ushort)qa[e] << 8);
        }
    };
    float4 bv0, bv1;
    stageAsync(0, 0);
    if (TRB) { loadBT(0, bv0, bv1); writeBT(0, bv0, bv1); }
    __syncthreads();
    int cur = 0;
    for (int kk = 0; kk < K; kk += 64) {
        int nxt = cur ^ 1;
        bool more = (kk + 64) < K;
        if (more) {
            stageAsync(nxt, kk + 64);
            if (TRB) loadBT(kk + 64, bv0, bv1);   // regs; written after MFMAs
        }
        mfmaStep(cur);
        if (more && TRB) writeBT(nxt, bv0, bv1);
        __syncthreads();
        cur = nxt;
    }
    #pragma unroll
    for (int i = 0; i < 4; ++i) {
        int rowb = r0 + wr*64 + i*16 + q*4;
        #pragma unroll
        for (int j = 0; j < 4; ++j) {
            int col = n0 + wc*64 + j*16 + c16;
            #pragma unroll
            for (int r = 0; r < 4; ++r) {
                float v = acc[i][j][r] * oscale;
                v = fminf(fmaxf(v, -448.0f), 448.0f);
                outp[(size_t)(rowb + r)*NC + col] = f2fp8(v);
            }
        }
    }
}

// ---------------------------------------------------------------------------
// F1: single-pass online softmax-over-b stats for fp8 t1,t2. m and 1/d out.
// ---------------------------------------------------------------------------
__global__ __launch_bounds__(512) void kF1q(
    const uchar* __restrict__ t1, const uchar* __restrict__ t2,
    float* __restrict__ m1, float* __restrict__ rd1,
    float* __restrict__ m2, float* __restrict__ rd2)
{
    int s = blockIdx.x;
    int t = threadIdx.x;
    int hq = t & 63;
    int bq = t >> 6;
    const size_t str = (size_t)SIGx*HIDx;
    size_t base = (size_t)(bq*32)*str + (size_t)s*HIDx + hq*4;

    float mv1[4], dv1[4], mv2[4], dv2[4];
    #pragma unroll
    for (int e = 0; e < 4; ++e) { mv1[e]=-3.0e38f; dv1[e]=0.0f; mv2[e]=-3.0e38f; dv2[e]=0.0f; }

    for (int i = 0; i < 32; ++i) {
        uint u1 = *(const uint*)(t1 + base + (size_t)i*str);
        uint u2 = *(const uint*)(t2 + base + (size_t)i*str);
        float v1[4], v2[4];
        v1[0] = __builtin_amdgcn_cvt_f32_fp8(u1, 0);
        v1[1] = __builtin_amdgcn_cvt_f32_fp8(u1, 1);
        v1[2] = __builtin_amdgcn_cvt_f32_fp8(u1, 2);
        v1[3] = __builtin_amdgcn_cvt_f32_fp8(u1, 3);
        v2[0] = __builtin_amdgcn_cvt_f32_fp8(u2, 0);
        v2[1] = __builtin_amdgcn_cvt_f32_fp8(u2, 1);
        v2[2] = __builtin_amdgcn_cvt_f32_fp8(u2, 2);
        v2[3] = __builtin_amdgcn_cvt_f32_fp8(u2, 3);
        #pragma unroll
        for (int e = 0; e < 4; ++e) {
            float mn;
            mn = fmaxf(mv1[e], v1[e]);
            dv1[e] = dv1[e]*__expf(mv1[e]-mn) + __expf(v1[e]-mn); mv1[e] = mn;
            mn = fmaxf(mv2[e], v2[e]);
            dv2[e] = dv2[e]*__expf(mv2[e]-mn) + __expf(v2[e]-mn); mv2[e] = mn;
        }
    }

    __shared__ float pm1[8][256], pd1[8][256], pm2[8][256], pd2[8][256];
    #pragma unroll
    for (int e = 0; e < 4; ++e) {
        pm1[bq][hq*4+e] = mv1[e]; pd1[bq][hq*4+e] = dv1[e];
        pm2[bq][hq*4+e] = mv2[e]; pd2[bq][hq*4+e] = dv2[e];
    }
    __syncthreads();

    if (t < 256) {
        int h = t;
        float m = -3.0e38f, d = 0.0f;
        #pragma unroll
        for (int j = 0; j < 8; ++j) {
            float mm = pm1[j][h], dd = pd1[j][h];
            float mn = fmaxf(m, mm);
            d = d*__expf(m-mn) + dd*__expf(mm-mn);
            m = mn;
        }
        size_t o = (size_t)s*HIDx + h;
        m1[o] = m; rd1[o] = 1.0f/d;
    } else {
        int h = t - 256;
        float m = -3.0e38f, d = 0.0f;
        #pragma unroll
        for (int j = 0; j < 8; ++j) {
            float mm = pm2[j][h], dd = pd2[j][h];
            float mn = fmaxf(m, mm);
            d = d*__expf(m-mn) + dd*__expf(mm-mn);
            m = mn;
        }
        size_t o = (size_t)s*HIDx + h;
        m2[o] = m; rd2[o] = 1.0f/d;
    }
}

// ---------------------------------------------------------------------------
// F2: sig[b,s] = sum_h exp(t1-m1)*rd1 + exp(t2-m2)*rd2 (fp8 t).
// ---------------------------------------------------------------------------
__global__ __launch_bounds__(256) void kF2q(
    const uchar* __restrict__ t1, const uchar* __restrict__ t2,
    const float* __restrict__ m1, const float* __restrict__ rd1,
    const float* __restrict__ m2, const float* __restrict__ rd2,
    float* __restrict__ sig)
{
    int b = blockIdx.y;
    int sq = threadIdx.x >> 6;
    int s = blockIdx.x*4 + sq;
    int hq = threadIdx.x & 63;
    size_t sh = (size_t)s*HIDx + hq*4;
    size_t tb = ((size_t)b*SIGx + s)*HIDx + hq*4;
    uint u1 = *(const uint*)(t1 + tb);
    uint u2 = *(const uint*)(t2 + tb);
    f32x4 a1 = *(const f32x4*)&m1[sh];
    f32x4 r1 = *(const f32x4*)&rd1[sh];
    f32x4 a2 = *(const f32x4*)&m2[sh];
    f32x4 r2 = *(const f32x4*)&rd2[sh];
    float v = 0.0f;
    v += __expf(__builtin_amdgcn_cvt_f32_fp8(u1,0) - a1.x) * r1.x;
    v += __expf(__builtin_amdgcn_cvt_f32_fp8(u1,1) - a1.y) * r1.y;
    v += __expf(__builtin_amdgcn_cvt_f32_fp8(u1,2) - a1.z) * r1.z;
    v += __expf(__builtin_amdgcn_cvt_f32_fp8(u1,3) - a1.w) * r1.w;
    v += __expf(__builtin_amdgcn_cvt_f32_fp8(u2,0) - a2.x) * r2.x;
    v += __expf(__builtin_amdgcn_cvt_f32_fp8(u2,1) - a2.y) * r2.y;
    v += __expf(__builtin_amdgcn_cvt_f32_fp8(u2,2) - a2.z) * r2.z;
    v += __expf(__builtin_amdgcn_cvt_f32_fp8(u2,3) - a2.w) * r2.w;

    __shared__ float red[256];
    red[threadIdx.x] = v;
    __syncthreads();
    for (int st = 32; st > 0; st >>= 1) {
        if (hq < st) red[threadIdx.x] += red[threadIdx.x + st];
        __syncthreads();
    }
    if (hq == 0) sig[(size_t)b*SIGx + s] = red[sq*64];
}

// ---------------------------------------------------------------------------
// G: out[b,:] = softmax(sig[b,:] @ fcf_w.T + fcf_b)
// ---------------------------------------------------------------------------
__global__ __launch_bounds__(256) void kG_out(
    const float* __restrict__ sig, const float* __restrict__ fw,
    const float* __restrict__ fb, float* __restrict__ out)
{
    int b = blockIdx.x;
    int tid = threadIdx.x;
    __shared__ float red[256];
    __shared__ float logits[OUTx];
    float sv = sig[(size_t)b*SIGx + tid];
    for (int o = 0; o < OUTx; ++o) {
        red[tid] = sv * fw[o*SIGx + tid];
        __syncthreads();
        for (int st = 128; st > 0; st >>= 1) {
            if (tid < st) red[tid] += red[tid+st];
            __syncthreads();
        }
        if (tid == 0) logits[o] = red[0] + fb[o];
        __syncthreads();
    }
    if (tid == 0) {
        float mx = logits[0];
        for (int o = 1; o < OUTx; ++o) mx = fmaxf(mx, logits[o]);
        float dd = 0.0f; float e[OUTx];
        for (int o = 0; o < OUTx; ++o) { e[o] = expf(logits[o]-mx); dd += e[o]; }
        float inv = 1.0f/dd;
        for (int o = 0; o < OUTx; ++o) out[(size_t)b*OUTx + o] = e[o]*inv;
    }
}

// ---------------------------------------------------------------------------
static inline size_t alignup(size_t b) { return (b + 255) & ~(size_t)255; }

extern "C" void kernel_launch(void* const* d_in, const int* in_sizes, int n_in,
                              void* d_out, int out_size, void* d_ws, size_t ws_size,
                              hipStream_t stream)
{
    const float* x   = (const float*)d_in[0];
    // d_in[1] = unif -- dead
    const float* z   = (const float*)d_in[2];
    const float* mg  = (const float*)d_in[3];
    const float* w1  = (const float*)d_in[4];
    const float* b1  = (const float*)d_in[5];
    const float* w2  = (const float*)d_in[6];
    const float* b2  = (const float*)d_in[7];
    const float* c1  = (const float*)d_in[8];
    const float* c2  = (const float*)d_in[9];
    const float* fw  = (const float*)d_in[10];
    const float* fbv = (const float*)d_in[11];
    float* out = (float*)d_out;
    float* flp = out + (size_t)Bx*OUTx;
    (void)in_sizes; (void)n_in; (void)out_size;

    char* ws = (char*)d_ws;
    size_t off = 0;
    auto alloc = [&](size_t bytes) -> char* {
        char* p = ws + off; off += alignup(bytes); return p;
    };
    float*  feat = (float*)alloc((size_t)Bx*Nx*3*4);
    uchar*  c1q  = (uchar*)alloc((size_t)SIGx*Nx);
    uchar*  c2q  = (uchar*)alloc((size_t)SIGx*Nx);
    uchar*  w2tq = (uchar*)alloc((size_t)HIDx*HIDx);
    uchar*  t1   = (uchar*)alloc((size_t)Bx*SIGx*HIDx);   // fp8 t
    uchar*  t2   = (uchar*)alloc((size_t)Bx*SIGx*HIDx);
    float*  m1   = (float*)alloc((size_t)SIGx*HIDx*4);
    float*  d1   = (float*)alloc((size_t)SIGx*HIDx*4);
    float*  m2   = (float*)alloc((size_t)SIGx*HIDx*4);
    float*  d2   = (float*)alloc((size_t)SIGx*HIDx*4);
    float*  sig  = (float*)alloc((size_t)Bx*SIGx*4);
    size_t fixed = off;

    int BC = 1;
    for (int c = Bx; c >= 1; c >>= 1) {
        size_t need = fixed + alignup((size_t)c*Nx*Nx)
                            + 2*alignup((size_t)c*HIDx*Nx);
        if (need <= ws_size) { BC = c; break; }
    }
    uchar* Padj = (uchar*)alloc((size_t)BC*Nx*Nx);       // adj fp8
    uchar* P1   = (uchar*)alloc((size_t)BC*HIDx*Nx);     // h2q
    uchar* P2   = (uchar*)alloc((size_t)BC*HIDx*Nx);     // s1q / s2q

    hipLaunchKernelGGL(kA_sample, dim3(Bx), dim3(Nx), 0, stream, x, z, mg, feat, flp);
    hipLaunchKernelGGL(kPrep, dim3(512), dim3(256), 0, stream, c1, c2, w2, c1q, c2q, w2tq);

    const int nch = Bx / BC;
    for (int c = 0; c < nch; ++c) {
        int b0 = c * BC;
        const float* featL = feat + (size_t)b0*Nx*3;
        uchar* t1L = t1 + (size_t)b0*SIGx*HIDx;
        uchar* t2L = t2 + (size_t)b0*SIGx*HIDx;
        // adj (fp8) + rank-3 pass-1 -> s1q
        hipLaunchKernelGGL(kFuse1, dim3(BC), dim3(512), 0, stream,
                           featL, w1, b1, Padj, P2);
        // t1 = (1/16) * c1q @ s1q -> fp8   (8-wave)
        hipLaunchKernelGGL(kGstd8, dim3(BC, 4), dim3(512), 0, stream,
                           c1q, P2, t1L, 0.0625f);
        // h2q = (1/16) * w2tq @ s1q^T-staged -> fp8  (TRB, 4-wave)
        hipLaunchKernelGGL((kGstdP<256,512,true>), dim3(BC, 8), dim3(256), 0, stream,
                           w2tq, P2, P1, 0.0625f);
        // s2q = 0.25 * relu(h2q @ adj + b2) -> fp8  (8-wave counted-vmcnt)
        hipLaunchKernelGGL(kGemmAdj8, dim3(BC, 8), dim3(512), 0, stream, P1, Padj, b2, P2);
        // t2 = 0.25 * c2q @ s2q  (16 * 1/4 undone) -> fp8  (8-wave)
        hipLaunchKernelGGL(kGstd8, dim3(BC, 4), dim3(512), 0, stream,
                           c2q, P2, t2L, 0.25f);
    }

    hipLaunchKernelGGL(kF1q, dim3(SIGx), dim3(512), 0, stream,
                       t1, t2, m1, d1, m2, d2);
    hipLaunchKernelGGL(kF2q, dim3(SIGx/4, Bx), dim3(256), 0, stream,
                       t1, t2, m1, d1, m2, d2, sig);
    hipLaunchKernelGGL(kG_out, dim3(Bx), dim3(256), 0, stream, sig, fw, fbv, out);
}

// Round 6
// 288.448 us; speedup vs baseline: 1.2283x; 1.0027x over previous
//
#include <hip/hip_runtime.h>
#include <hip/hip_bf16.h>
#include <math.h>

#define Bx   256
#define Nx   512
#define SIGx 256
#define HIDx 256
#define OUTx 10
#define Hx   256

typedef __attribute__((ext_vector_type(4))) float f32x4;
typedef __attribute__((ext_vector_type(2))) uint uint2v;
typedef long fp8x8;          // 8 fp8 bytes = 2 VGPRs (MFMA A/B operand)
typedef unsigned char uchar;

#define WAITVM(N) asm volatile("s_waitcnt vmcnt(" #N ")" ::: "memory")
#define MEMFENCE() asm volatile("" ::: "memory")

__device__ inline uchar f2fp8(float v) {
    int r = __builtin_amdgcn_cvt_pk_fp8_f32(v, 0.0f, 0, false);
    return (uchar)(r & 0xff);
}
__device__ inline uint pk4fp8(float a0, float a1, float a2, float a3) {
    int r = __builtin_amdgcn_cvt_pk_fp8_f32(a0, a1, 0, false);
    r = __builtin_amdgcn_cvt_pk_fp8_f32(a2, a3, r, true);
    return (uint)r;
}

// async global->LDS, 16B per lane; lds dest = wave-uniform base + lane*16
__device__ inline void gload_lds16(const uchar* g, uchar* l) {
    __builtin_amdgcn_global_load_lds(
        (const __attribute__((address_space(1))) uint*)g,
        (__attribute__((address_space(3))) uint*)l, 16, 0, 0);
}
// swizzled LDS fragment address: 64B rows, 16B-unit XOR swizzle
__device__ inline const uchar* laddr(const uchar* base, int row, int kb) {
    int ps = (kb >> 4) ^ ((row >> 1) & 3) ^ ((row >> 4) & 3);
    return base + row*64 + ps*16 + (kb & 15);
}

// ---------------------------------------------------------------------------
// Kernel A: sampling stage (mixture fields constant over m => unif dead).
// ---------------------------------------------------------------------------
__global__ __launch_bounds__(512) void kA_sample(
    const float* __restrict__ x, const float* __restrict__ z,
    const float* __restrict__ mg, float* __restrict__ feat,
    float* __restrict__ flp)
{
    int b = blockIdx.x;
    int n = threadIdx.x;
    int g = n >> 5;
    float mux = mg[g*6+1];
    float muy = mg[g*6+2];
    float sxv = expf(mg[g*6+3]);
    float syv = expf(mg[g*6+4]);
    float rho = tanhf(mg[g*6+5]);
    float z1 = z[((size_t)b*Nx + n)*2 + 0];
    float z2 = z[((size_t)b*Nx + n)*2 + 1];
    float omr2 = 1.0f - rho*rho;
    float xs = mux + sxv*z1;
    float ys = muy + syv*(rho*z1 + sqrtf(omr2)*z2);
    float dx = xs - mux, dy = ys - muy;
    float quad = (dx*dx/(sxv*sxv) - 2.0f*rho*dx*dy/(sxv*syv) + dy*dy/(syv*syv)) / omr2;
    float logprob = -1.8378770664093453f - logf(sxv*syv) - 0.5f*logf(omr2) - 0.5f*quad;
    float lx = tanhf(xs), ly = tanhf(ys);
    int px = (int)truncf(0.5f*(lx+1.0f)*(float)Hx - 0.1f);
    int py = (int)truncf(0.5f*(ly+1.0f)*(float)Hx - 0.1f);
    px = px < 0 ? 0 : (px > Hx-1 ? Hx-1 : px);
    py = py < 0 ? 0 : (py > Hx-1 ? Hx-1 : py);
    float pv = x[(size_t)b*Hx*Hx + (size_t)px*Hx + py];
    size_t fo = ((size_t)b*Nx + n)*3;
    feat[fo+0] = pv; feat[fo+1] = lx; feat[fo+2] = ly;

    __shared__ float red[512];
    red[n] = logprob;
    __syncthreads();
    for (int st = 256; st > 0; st >>= 1) {
        if (n < st) red[n] += red[n+st];
        __syncthreads();
    }
    if (n == 0) flp[b] = red[0];
}

// ---------------------------------------------------------------------------
// Prep: c1,c2 -> fp8 (x16 scale); w2 -> w2t fp8 (x16, transposed).
// ---------------------------------------------------------------------------
__global__ __launch_bounds__(256) void kPrep(
    const float* __restrict__ c1, const float* __restrict__ c2,
    const float* __restrict__ w2,
    uchar* __restrict__ c1q, uchar* __restrict__ c2q, uchar* __restrict__ w2tq)
{
    int idx = blockIdx.x*256 + threadIdx.x;
    if (idx < SIGx*Nx) {
        c1q[idx] = f2fp8(16.0f * c1[idx]);
        c2q[idx] = f2fp8(16.0f * c2[idx]);
    }
    if (idx < HIDx*HIDx) {
        int i = idx >> 8, j = idx & 255;
        w2tq[idx] = f2fp8(16.0f * w2[j*HIDx + i]);
    }
}

// ===========================================================================
// kFuse1: per b -- generate adj (fp8, materialized), accumulate
// G[c][n] = sum_m featT[c][m]*adj[m][n] fp32, rank-3 epilogue
// s1t[h][n] = relu(w1[.][h].G + b1[h]) -> fp8.   (round-0 form)
// ===========================================================================
__global__ __launch_bounds__(512) void kFuse1(
    const float* __restrict__ featL, const float* __restrict__ w1,
    const float* __restrict__ b1,
    uchar* __restrict__ adjAll, uchar* __restrict__ s1tAll)
{
    int b = blockIdx.x;
    const float* fb = featL + (size_t)b*Nx*3;
    uchar* adj = adjAll + (size_t)b*Nx*Nx;
    uchar* s1t = s1tAll + (size_t)b*HIDx*Nx;

    __shared__ float fpv[Nx], flx[Nx], fly[Nx], fH[Nx];
    __shared__ float w1s[3*HIDx], b1s[HIDx];
    __shared__ float Gp[4][3][Nx];

    int t = threadIdx.x;
    {
        float pv = fb[t*3+0], lx = fb[t*3+1], ly = fb[t*3+2];
        fpv[t] = pv; flx[t] = lx; fly[t] = ly;
        fH[t] = fmaf(0.5f*lx, lx, fmaf(0.5f*ly, ly, 1.0f));
    }
    for (int i = t; i < 3*HIDx; i += 512) w1s[i] = w1[i];
    if (t < HIDx) b1s[t] = b1[t];
    __syncthreads();

    int tq = t & 127;          // column-quad index: n = 4*tq .. 4*tq+3
    int mc = t >> 7;           // m-chunk 0..3 (128 m each)
    int n4 = tq*4;

    float xn[4], yn[4], cn[4];
    #pragma unroll
    for (int e = 0; e < 4; ++e) {
        xn[e] = flx[n4+e]; yn[e] = fly[n4+e];
        cn[e] = fmaf(0.5f*xn[e], xn[e], 0.5f*yn[e]*yn[e]);
    }
    float G0[4] = {}, G1[4] = {}, G2[4] = {};

    int m0 = mc*128;
    #pragma unroll 4
    for (int mm = 0; mm < 128; ++mm) {
        int m = m0 + mm;
        float hx = fH[m], fx = flx[m], fy = fly[m];
        float a[4];
        #pragma unroll
        for (int e = 0; e < 4; ++e) {
            float s = fmaf(-yn[e], fy, fmaf(-xn[e], fx, hx + cn[e]));
            a[e] = __builtin_amdgcn_rcpf(s);
            G0[e] = fmaf(a[e], fpv[m], G0[e]);
            G1[e] = fmaf(a[e], fx, G1[e]);
            G2[e] = fmaf(a[e], fy, G2[e]);
        }
        *(uint*)(adj + (size_t)m*Nx + n4) = pk4fp8(a[0], a[1], a[2], a[3]);
    }

    *(f32x4*)&Gp[mc][0][n4] = (f32x4){G0[0],G0[1],G0[2],G0[3]};
    *(f32x4*)&Gp[mc][1][n4] = (f32x4){G1[0],G1[1],G1[2],G1[3]};
    *(f32x4*)&Gp[mc][2][n4] = (f32x4){G2[0],G2[1],G2[2],G2[3]};
    __syncthreads();

    f32x4 T0 = {}, T1 = {}, T2 = {};
    #pragma unroll
    for (int j = 0; j < 4; ++j) {
        T0 += *(const f32x4*)&Gp[j][0][n4];
        T1 += *(const f32x4*)&Gp[j][1][n4];
        T2 += *(const f32x4*)&Gp[j][2][n4];
    }

    int hc = mc;
    #pragma unroll 4
    for (int hh = 0; hh < 64; ++hh) {
        int h = hc*64 + hh;
        float w0 = w1s[h], wA = w1s[HIDx+h], wB = w1s[2*HIDx+h], bb = b1s[h];
        float v0 = fminf(fmaxf(fmaf(T0.x,w0, fmaf(T1.x,wA, fmaf(T2.x,wB, bb))), 0.0f), 448.0f);
        float v1 = fminf(fmaxf(fmaf(T0.y,w0, fmaf(T1.y,wA, fmaf(T2.y,wB, bb))), 0.0f), 448.0f);
        float v2 = fminf(fmaxf(fmaf(T0.z,w0, fmaf(T1.z,wA, fmaf(T2.z,wB, bb))), 0.0f), 448.0f);
        float v3 = fminf(fmaxf(fmaf(T0.w,w0, fmaf(T1.w,wA, fmaf(T2.w,wB, bb))), 0.0f), 448.0f);
        *(uint*)(s1t + (size_t)h*Nx + n4) = pk4fp8(v0, v1, v2, v3);
    }
}

// ===========================================================================
// kGemmAdj8: s2t[h][n] = 0.25*relu(sum_m h2t[h][m]*adj[m][n]+b2[h]).
// 8-wave, 2-BUFFER counted-vmcnt: 32KB LDS -> 3 blocks/CU (24 waves, was 2).
// Per K-step: stage t_{i+1} -> WAITVM(2) (t_{i+1}'s loads stay in flight
// across the barrier) -> s_barrier -> MFMA(buf i&1) -> s_barrier.
// ===========================================================================
__global__ __launch_bounds__(512, 4) void kGemmAdj8(
    const uchar* __restrict__ Aall, const uchar* __restrict__ adjAll,
    const float* __restrict__ bias, uchar* __restrict__ outAll)
{
    int b    = blockIdx.x;
    int tile = blockIdx.y;
    int rt = tile >> 2;
    int ct = tile & 3;
    const uchar* A = Aall + (size_t)b*HIDx*Nx;
    const uchar* Badj = adjAll + (size_t)b*Nx*Nx;
    uchar* outp = outAll + (size_t)b*HIDx*Nx;

    __shared__ __align__(16) uchar Als[2][128*64];
    __shared__ __align__(16) uchar Bls[2][128*64];
    int t = threadIdx.x;
    int lane = t & 63, wave = t >> 6;
    int wr = wave >> 2, wc = wave & 3;       // 2x4 wave grid, 64x32 each
    int q = lane >> 4, c16 = lane & 15;
    int r0 = rt*128, n0 = ct*128;
    int srow = wave*16 + (lane >> 2);        // staging row (one chunk/wave)
    int pu   = lane & 3;
    int sl   = pu ^ ((srow>>1)&3) ^ ((srow>>4)&3);
    f32x4 acc[4][2] = {};

    auto stage = [&](int buf, int kkv) {     // 2 loads per thread
        gload_lds16(A + (size_t)(r0+srow)*Nx + kkv + sl*16, Als[buf] + wave*1024);
        gload_lds16(Badj + (size_t)(n0+srow)*Nx + kkv + sl*16, Bls[buf] + wave*1024);
    };

    const int nt = Nx/64;      // 8
    stage(0, 0);
    for (int i = 0; i < nt; ++i) {
        if (i < nt-1) { stage((i+1)&1, (i+1)*64); WAITVM(2); }
        else WAITVM(0);
        __builtin_amdgcn_s_barrier();
        MEMFENCE();
        const uchar* Ac = Als[i&1];
        const uchar* Bc = Bls[i&1];
        #pragma unroll
        for (int ks = 0; ks < 64; ks += 32) {
            fp8x8 af[4], bfr[2];
            #pragma unroll
            for (int i2 = 0; i2 < 4; ++i2)
                af[i2] = *(const fp8x8*)laddr(Ac, wr*64 + i2*16 + c16, ks + q*8);
            #pragma unroll
            for (int j = 0; j < 2; ++j)
                bfr[j] = *(const fp8x8*)laddr(Bc, wc*32 + j*16 + c16, ks + q*8);
            #pragma unroll
            for (int i2 = 0; i2 < 4; ++i2)
                #pragma unroll
                for (int j = 0; j < 2; ++j)
                    acc[i2][j] = __builtin_amdgcn_mfma_f32_16x16x32_fp8_fp8(af[i2], bfr[j], acc[i2][j], 0, 0, 0);
        }
        MEMFENCE();
        __builtin_amdgcn_s_barrier();        // write-after-read protect
        MEMFENCE();
    }
    #pragma unroll
    for (int i = 0; i < 4; ++i) {
        int rowb = r0 + wr*64 + i*16 + q*4;
        #pragma unroll
        for (int j = 0; j < 2; ++j) {
            int col = n0 + wc*32 + j*16 + c16;
            #pragma unroll
            for (int r = 0; r < 4; ++r) {
                float v = fmaxf(acc[i][j][r] + bias[rowb + r], 0.0f) * 0.25f;
                outp[(size_t)(rowb + r)*Nx + col] = f2fp8(fminf(v, 448.0f));
            }
        }
    }
}

// ===========================================================================
// kGstd8: C[row][col] = oscale * sum_k A[row][k]*B[k][col]; K=512, NC=256.
// Same 8-wave / acc[4][2] / 2-buffer counted-vmcnt structure as kGemmAdj8.
// ===========================================================================
__global__ __launch_bounds__(512, 4) void kGstd8(
    const uchar* __restrict__ Ash, const uchar* __restrict__ Ball,
    uchar* __restrict__ outAll, float oscale)
{
    int b    = blockIdx.x;
    int tile = blockIdx.y;                   // 0..3
    int rt = tile >> 1;
    int ct = tile & 1;
    const uchar* B = Ball + (size_t)b*HIDx*Nx;
    uchar* outp = outAll + (size_t)b*HIDx*256;

    __shared__ __align__(16) uchar Als[2][128*64];
    __shared__ __align__(16) uchar Bls[2][128*64];
    int t = threadIdx.x;
    int lane = t & 63, wave = t >> 6;
    int wr = wave >> 2, wc = wave & 3;
    int q = lane >> 4, c16 = lane & 15;
    int r0 = rt*128, n0 = ct*128;
    int srow = wave*16 + (lane >> 2);
    int pu   = lane & 3;
    int sl   = pu ^ ((srow>>1)&3) ^ ((srow>>4)&3);
    f32x4 acc[4][2] = {};

    auto stage = [&](int buf, int kkv) {
        gload_lds16(Ash + (size_t)(r0+srow)*Nx + kkv + sl*16, Als[buf] + wave*1024);
        gload_lds16(B + (size_t)(n0+srow)*Nx + kkv + sl*16, Bls[buf] + wave*1024);
    };

    const int nt = Nx/64;      // 8
    stage(0, 0);
    for (int i = 0; i < nt; ++i) {
        if (i < nt-1) { stage((i+1)&1, (i+1)*64); WAITVM(2); }
        else WAITVM(0);
        __builtin_amdgcn_s_barrier();
        MEMFENCE();
        const uchar* Ac = Als[i&1];
        const uchar* Bc = Bls[i&1];
        #pragma unroll
        for (int ks = 0; ks < 64; ks += 32) {
            fp8x8 af[4], bfr[2];
            #pragma unroll
            for (int i2 = 0; i2 < 4; ++i2)
                af[i2] = *(const fp8x8*)laddr(Ac, wr*64 + i2*16 + c16, ks + q*8);
            #pragma unroll
            for (int j = 0; j < 2; ++j)
                bfr[j] = *(const fp8x8*)laddr(Bc, wc*32 + j*16 + c16, ks + q*8);
            #pragma unroll
            for (int i2 = 0; i2 < 4; ++i2)
                #pragma unroll
                for (int j = 0; j < 2; ++j)
                    acc[i2][j] = __builtin_amdgcn_mfma_f32_16x16x32_fp8_fp8(af[i2], bfr[j], acc[i2][j], 0, 0, 0);
        }
        MEMFENCE();
        __builtin_amdgcn_s_barrier();
        MEMFENCE();
    }
    #pragma unroll
    for (int i = 0; i < 4; ++i) {
        int rowb = r0 + wr*64 + i*16 + q*4;
        #pragma unroll
        for (int j = 0; j < 2; ++j) {
            int col = n0 + wc*32 + j*16 + c16;
            #pragma unroll
            for (int r = 0; r < 4; ++r) {
                float v = acc[i][j][r] * oscale;
                v = fminf(fmaxf(v, -448.0f), 448.0f);
                outp[(size_t)(rowb + r)*256 + col] = f2fp8(v);
            }
        }
    }
}

// ===========================================================================
// kGstdT8: h2[h][n] = oscale * sum_k w2t[h][k] * s1t[n-col][k]-transposed.
// 8-WAVE TRB: 512 thr; A async-staged (1 load/thread); B = VGPR transpose
// staging (each thread: 2 k's x 8 cols), 2-phase __syncthreads loop.
// K=256 (A stride), NC=512 (B row len / out stride). acc[4][2], 32KB LDS.
// ===========================================================================
__global__ __launch_bounds__(512, 4) void kGstdT8(
    const uchar* __restrict__ Ash, const uchar* __restrict__ Ball,
    uchar* __restrict__ outAll, float oscale)
{
    const int K = 256, NC = 512;
    int b    = blockIdx.x;
    int tile = blockIdx.y;          // 0..7
    int rt = tile >> 2;             // 0..1
    int ct = tile & 3;              // 0..3
    const uchar* B = Ball + (size_t)b*HIDx*Nx;   // s1t: 256 rows x 512
    uchar* outp = outAll + (size_t)b*HIDx*NC;

    __shared__ __align__(16) uchar Als[2][128*64];
    __shared__ __align__(16) uchar Bls[2][128*64];
    int t = threadIdx.x;
    int lane = t & 63, wave = t >> 6;
    int wr = wave >> 2, wc = wave & 3;
    int q = lane >> 4, c16 = lane & 15;
    int r0 = rt*128, n0 = ct*128;
    int srow = wave*16 + (lane >> 2);
    int pu   = lane & 3;
    int sl   = pu ^ ((srow>>1)&3) ^ ((srow>>4)&3);
    int pi  = t & 31;               // k-pair within 64-k tile
    int g   = t >> 5;               // 0..15
    int nc8 = g & 7;                // col group of 16
    int ch  = g >> 3;               // 8-col half within group
    f32x4 acc[4][2] = {};

    auto stageA = [&](int buf, int kkv) {
        gload_lds16(Ash + (size_t)(r0+srow)*K + kkv + sl*16, Als[buf] + wave*1024);
    };
    auto loadBT = [&](int kkv, uint2v& v0, uint2v& v1) {
        int hk = kkv + 2*pi;
        const uchar* g0 = B + (size_t)hk*NC + n0 + nc8*16 + ch*8;
        v0 = *(const uint2v*)g0;
        v1 = *(const uint2v*)(g0 + NC);
    };
    auto writeBT = [&](int buf, const uint2v& v0, const uint2v& v1) {
        const uchar* pa = (const uchar*)&v0;
        const uchar* qa = (const uchar*)&v1;
        int kb = 2*pi;
        int s  = kb >> 4;
        #pragma unroll
        for (int e = 0; e < 8; ++e) {
            int row = nc8*16 + ch*8 + e;
            int ps = s ^ ((row>>1)&3) ^ ((row>>4)&3);
            *(ushort*)(Bls[buf] + row*64 + ps*16 + (kb & 15)) =
                (ushort)pa[e] | ((ushort)qa[e] << 8);
        }
    };
    auto mfmaStep = [&](int buf) {
        const uchar* Ac = Als[buf];
        const uchar* Bc = Bls[buf];
        #pragma unroll
        for (int ks = 0; ks < 64; ks += 32) {
            fp8x8 af[4], bfr[2];
            #pragma unroll
            for (int i = 0; i < 4; ++i)
                af[i] = *(const fp8x8*)laddr(Ac, wr*64 + i*16 + c16, ks + q*8);
            #pragma unroll
            for (int j = 0; j < 2; ++j)
                bfr[j] = *(const fp8x8*)laddr(Bc, wc*32 + j*16 + c16, ks + q*8);
            #pragma unroll
            for (int i = 0; i < 4; ++i)
                #pragma unroll
                for (int j = 0; j < 2; ++j)
                    acc[i][j] = __builtin_amdgcn_mfma_f32_16x16x32_fp8_fp8(af[i], bfr[j], acc[i][j], 0, 0, 0);
        }
    };

    uint2v bv0, bv1;
    stageA(0, 0);
    loadBT(0, bv0, bv1); writeBT(0, bv0, bv1);
    __syncthreads();
    for (int kk = 0; kk < K; kk += 64) {
        int cur = (kk >> 6) & 1, nxt = cur ^ 1;
        bool more = (kk + 64) < K;
        if (more) {
            stageA(nxt, kk + 64);
            loadBT(kk + 64, bv0, bv1);   // regs; written after MFMAs
        }
        mfmaStep(cur);
        if (more) writeBT(nxt, bv0, bv1);
        __syncthreads();
    }
    #pragma unroll
    for (int i = 0; i < 4; ++i) {
        int rowb = r0 + wr*64 + i*16 + q*4;
        #pragma unroll
        for (int j = 0; j < 2; ++j) {
            int col = n0 + wc*32 + j*16 + c16;
            #pragma unroll
            for (int r = 0; r < 4; ++r) {
                float v = acc[i][j][r] * oscale;
                v = fminf(fmaxf(v, -448.0f), 448.0f);
                outp[(size_t)(rowb + r)*NC + col] = f2fp8(v);
            }
        }
    }
}

// ---------------------------------------------------------------------------
// F1: single-pass online softmax-over-b stats for fp8 t1,t2. m and 1/d out.
// ---------------------------------------------------------------------------
__global__ __launch_bounds__(512) void kF1q(
    const uchar* __restrict__ t1, const uchar* __restrict__ t2,
    float* __restrict__ m1, float* __restrict__ rd1,
    float* __restrict__ m2, float* __restrict__ rd2)
{
    int s = blockIdx.x;
    int t = threadIdx.x;
    int hq = t & 63;
    int bq = t >> 6;
    const size_t str = (size_t)SIGx*HIDx;
    size_t base = (size_t)(bq*32)*str + (size_t)s*HIDx + hq*4;

    float mv1[4], dv1[4], mv2[4], dv2[4];
    #pragma unroll
    for (int e = 0; e < 4; ++e) { mv1[e]=-3.0e38f; dv1[e]=0.0f; mv2[e]=-3.0e38f; dv2[e]=0.0f; }

    for (int i = 0; i < 32; ++i) {
        uint u1 = *(const uint*)(t1 + base + (size_t)i*str);
        uint u2 = *(const uint*)(t2 + base + (size_t)i*str);
        float v1[4], v2[4];
        v1[0] = __builtin_amdgcn_cvt_f32_fp8(u1, 0);
        v1[1] = __builtin_amdgcn_cvt_f32_fp8(u1, 1);
        v1[2] = __builtin_amdgcn_cvt_f32_fp8(u1, 2);
        v1[3] = __builtin_amdgcn_cvt_f32_fp8(u1, 3);
        v2[0] = __builtin_amdgcn_cvt_f32_fp8(u2, 0);
        v2[1] = __builtin_amdgcn_cvt_f32_fp8(u2, 1);
        v2[2] = __builtin_amdgcn_cvt_f32_fp8(u2, 2);
        v2[3] = __builtin_amdgcn_cvt_f32_fp8(u2, 3);
        #pragma unroll
        for (int e = 0; e < 4; ++e) {
            float mn;
            mn = fmaxf(mv1[e], v1[e]);
            dv1[e] = dv1[e]*__expf(mv1[e]-mn) + __expf(v1[e]-mn); mv1[e] = mn;
            mn = fmaxf(mv2[e], v2[e]);
            dv2[e] = dv2[e]*__expf(mv2[e]-mn) + __expf(v2[e]-mn); mv2[e] = mn;
        }
    }

    __shared__ float pm1[8][256], pd1[8][256], pm2[8][256], pd2[8][256];
    #pragma unroll
    for (int e = 0; e < 4; ++e) {
        pm1[bq][hq*4+e] = mv1[e]; pd1[bq][hq*4+e] = dv1[e];
        pm2[bq][hq*4+e] = mv2[e]; pd2[bq][hq*4+e] = dv2[e];
    }
    __syncthreads();

    if (t < 256) {
        int h = t;
        float m = -3.0e38f, d = 0.0f;
        #pragma unroll
        for (int j = 0; j < 8; ++j) {
            float mm = pm1[j][h], dd = pd1[j][h];
            float mn = fmaxf(m, mm);
            d = d*__expf(m-mn) + dd*__expf(mm-mn);
            m = mn;
        }
        size_t o = (size_t)s*HIDx + h;
        m1[o] = m; rd1[o] = 1.0f/d;
    } else {
        int h = t - 256;
        float m = -3.0e38f, d = 0.0f;
        #pragma unroll
        for (int j = 0; j < 8; ++j) {
            float mm = pm2[j][h], dd = pd2[j][h];
            float mn = fmaxf(m, mm);
            d = d*__expf(m-mn) + dd*__expf(mm-mn);
            m = mn;
        }
        size_t o = (size_t)s*HIDx + h;
        m2[o] = m; rd2[o] = 1.0f/d;
    }
}

// ---------------------------------------------------------------------------
// F2: sig[b,s] = sum_h exp(t1-m1)*rd1 + exp(t2-m2)*rd2 (fp8 t).
// ---------------------------------------------------------------------------
__global__ __launch_bounds__(256) void kF2q(
    const uchar* __restrict__ t1, const uchar* __restrict__ t2,
    const float* __restrict__ m1, const float* __restrict__ rd1,
    const float* __restrict__ m2, const float* __restrict__ rd2,
    float* __restrict__ sig)
{
    int b = blockIdx.y;
    int sq = threadIdx.x >> 6;
    int s = blockIdx.x*4 + sq;
    int hq = threadIdx.x & 63;
    size_t sh = (size_t)s*HIDx + hq*4;
    size_t tb = ((size_t)b*SIGx + s)*HIDx + hq*4;
    uint u1 = *(const uint*)(t1 + tb);
    uint u2 = *(const uint*)(t2 + tb);
    f32x4 a1 = *(const f32x4*)&m1[sh];
    f32x4 r1 = *(const f32x4*)&rd1[sh];
    f32x4 a2 = *(const f32x4*)&m2[sh];
    f32x4 r2 = *(const f32x4*)&rd2[sh];
    float v = 0.0f;
    v += __expf(__builtin_amdgcn_cvt_f32_fp8(u1,0) - a1.x) * r1.x;
    v += __expf(__builtin_amdgcn_cvt_f32_fp8(u1,1) - a1.y) * r1.y;
    v += __expf(__builtin_amdgcn_cvt_f32_fp8(u1,2) - a1.z) * r1.z;
    v += __expf(__builtin_amdgcn_cvt_f32_fp8(u1,3) - a1.w) * r1.w;
    v += __expf(__builtin_amdgcn_cvt_f32_fp8(u2,0) - a2.x) * r2.x;
    v += __expf(__builtin_amdgcn_cvt_f32_fp8(u2,1) - a2.y) * r2.y;
    v += __expf(__builtin_amdgcn_cvt_f32_fp8(u2,2) - a2.z) * r2.z;
    v += __expf(__builtin_amdgcn_cvt_f32_fp8(u2,3) - a2.w) * r2.w;

    __shared__ float red[256];
    red[threadIdx.x] = v;
    __syncthreads();
    for (int st = 32; st > 0; st >>= 1) {
        if (hq < st) red[threadIdx.x] += red[threadIdx.x + st];
        __syncthreads();
    }
    if (hq == 0) sig[(size_t)b*SIGx + s] = red[sq*64];
}

// ---------------------------------------------------------------------------
// G: out[b,:] = softmax(sig[b,:] @ fcf_w.T + fcf_b)
// ---------------------------------------------------------------------------
__global__ __launch_bounds__(256) void kG_out(
    const float* __restrict__ sig, const float* __restrict__ fw,
    const float* __restrict__ fb, float* __restrict__ out)
{
    int b = blockIdx.x;
    int tid = threadIdx.x;
    __shared__ float red[256];
    __shared__ float logits[OUTx];
    float sv = sig[(size_t)b*SIGx + tid];
    for (int o = 0; o < OUTx; ++o) {
        red[tid] = sv * fw[o*SIGx + tid];
        __syncthreads();
        for (int st = 128; st > 0; st >>= 1) {
            if (tid < st) red[tid] += red[tid+st];
            __syncthreads();
        }
        if (tid == 0) logits[o] = red[0] + fb[o];
        __syncthreads();
    }
    if (tid == 0) {
        float mx = logits[0];
        for (int o = 1; o < OUTx; ++o) mx = fmaxf(mx, logits[o]);
        float dd = 0.0f; float e[OUTx];
        for (int o = 0; o < OUTx; ++o) { e[o] = expf(logits[o]-mx); dd += e[o]; }
        float inv = 1.0f/dd;
        for (int o = 0; o < OUTx; ++o) out[(size_t)b*OUTx + o] = e[o]*inv;
    }
}

// ---------------------------------------------------------------------------
static inline size_t alignup(size_t b) { return (b + 255) & ~(size_t)255; }

extern "C" void kernel_launch(void* const* d_in, const int* in_sizes, int n_in,
                              void* d_out, int out_size, void* d_ws, size_t ws_size,
                              hipStream_t stream)
{
    const float* x   = (const float*)d_in[0];
    // d_in[1] = unif -- dead
    const float* z   = (const float*)d_in[2];
    const float* mg  = (const float*)d_in[3];
    const float* w1  = (const float*)d_in[4];
    const float* b1  = (const float*)d_in[5];
    const float* w2  = (const float*)d_in[6];
    const float* b2  = (const float*)d_in[7];
    const float* c1  = (const float*)d_in[8];
    const float* c2  = (const float*)d_in[9];
    const float* fw  = (const float*)d_in[10];
    const float* fbv = (const float*)d_in[11];
    float* out = (float*)d_out;
    float* flp = out + (size_t)Bx*OUTx;
    (void)in_sizes; (void)n_in; (void)out_size;

    char* ws = (char*)d_ws;
    size_t off = 0;
    auto alloc = [&](size_t bytes) -> char* {
        char* p = ws + off; off += alignup(bytes); return p;
    };
    float*  feat = (float*)alloc((size_t)Bx*Nx*3*4);
    uchar*  c1q  = (uchar*)alloc((size_t)SIGx*Nx);
    uchar*  c2q  = (uchar*)alloc((size_t)SIGx*Nx);
    uchar*  w2tq = (uchar*)alloc((size_t)HIDx*HIDx);
    uchar*  t1   = (uchar*)alloc((size_t)Bx*SIGx*HIDx);   // fp8 t
    uchar*  t2   = (uchar*)alloc((size_t)Bx*SIGx*HIDx);
    float*  m1   = (float*)alloc((size_t)SIGx*HIDx*4);
    float*  d1   = (float*)alloc((size_t)SIGx*HIDx*4);
    float*  m2   = (float*)alloc((size_t)SIGx*HIDx*4);
    float*  d2   = (float*)alloc((size_t)SIGx*HIDx*4);
    float*  sig  = (float*)alloc((size_t)Bx*SIGx*4);
    size_t fixed = off;

    int BC = 1;
    for (int c = Bx; c >= 1; c >>= 1) {
        size_t need = fixed + alignup((size_t)c*Nx*Nx)
                            + 2*alignup((size_t)c*HIDx*Nx);
        if (need <= ws_size) { BC = c; break; }
    }
    uchar* Padj = (uchar*)alloc((size_t)BC*Nx*Nx);       // adj fp8
    uchar* P1   = (uchar*)alloc((size_t)BC*HIDx*Nx);     // h2q
    uchar* P2   = (uchar*)alloc((size_t)BC*HIDx*Nx);     // s1q / s2q

    hipLaunchKernelGGL(kA_sample, dim3(Bx), dim3(Nx), 0, stream, x, z, mg, feat, flp);
    hipLaunchKernelGGL(kPrep, dim3(512), dim3(256), 0, stream, c1, c2, w2, c1q, c2q, w2tq);

    const int nch = Bx / BC;
    for (int c = 0; c < nch; ++c) {
        int b0 = c * BC;
        const float* featL = feat + (size_t)b0*Nx*3;
        uchar* t1L = t1 + (size_t)b0*SIGx*HIDx;
        uchar* t2L = t2 + (size_t)b0*SIGx*HIDx;
        // adj (fp8) + rank-3 pass-1 -> s1q
        hipLaunchKernelGGL(kFuse1, dim3(BC), dim3(512), 0, stream,
                           featL, w1, b1, Padj, P2);
        // t1 = (1/16) * c1q @ s1q -> fp8   (8-wave, 2-buf counted)
        hipLaunchKernelGGL(kGstd8, dim3(BC, 4), dim3(512), 0, stream,
                           c1q, P2, t1L, 0.0625f);
        // h2q = (1/16) * w2tq @ s1q^T-staged -> fp8  (8-wave TRB)
        hipLaunchKernelGGL(kGstdT8, dim3(BC, 8), dim3(512), 0, stream,
                           w2tq, P2, P1, 0.0625f);
        // s2q = 0.25 * relu(h2q @ adj + b2) -> fp8  (8-wave, 2-buf counted)
        hipLaunchKernelGGL(kGemmAdj8, dim3(BC, 8), dim3(512), 0, stream, P1, Padj, b2, P2);
        // t2 = 0.25 * c2q @ s2q  (16 * 1/4 undone) -> fp8
        hipLaunchKernelGGL(kGstd8, dim3(BC, 4), dim3(512), 0, stream,
                           c2q, P2, t2L, 0.25f);
    }

    hipLaunchKernelGGL(kF1q, dim3(SIGx), dim3(512), 0, stream,
                       t1, t2, m1, d1, m2, d2);
    hipLaunchKernelGGL(kF2q, dim3(SIGx/4, Bx), dim3(256), 0, stream,
                       t1, t2, m1, d1, m2, d2, sig);
    hipLaunchKernelGGL(kG_out, dim3(Bx), dim3(256), 0, stream, sig, fw, fbv, out);
}

// Round 7
// 279.121 us; speedup vs baseline: 1.2694x; 1.0334x over previous
//
#include <hip/hip_runtime.h>
#include <hip/hip_bf16.h>
#include <math.h>

#define Bx   256
#define Nx   512
#define SIGx 256
#define HIDx 256
#define OUTx 10
#define Hx   256

typedef __attribute__((ext_vector_type(4))) float f32x4;
typedef __attribute__((ext_vector_type(2))) uint uint2v;
typedef long fp8x8;          // 8 fp8 bytes = 2 VGPRs (MFMA A/B operand)
typedef unsigned char uchar;

#define WAITVM(N) asm volatile("s_waitcnt vmcnt(" #N ")" ::: "memory")
#define MEMFENCE() asm volatile("" ::: "memory")

__device__ inline uchar f2fp8(float v) {
    int r = __builtin_amdgcn_cvt_pk_fp8_f32(v, 0.0f, 0, false);
    return (uchar)(r & 0xff);
}
__device__ inline uint pk4fp8(float a0, float a1, float a2, float a3) {
    int r = __builtin_amdgcn_cvt_pk_fp8_f32(a0, a1, 0, false);
    r = __builtin_amdgcn_cvt_pk_fp8_f32(a2, a3, r, true);
    return (uint)r;
}

// async global->LDS, 16B per lane; lds dest = wave-uniform base + lane*16
__device__ inline void gload_lds16(const uchar* g, uchar* l) {
    __builtin_amdgcn_global_load_lds(
        (const __attribute__((address_space(1))) uint*)g,
        (__attribute__((address_space(3))) uint*)l, 16, 0, 0);
}
// swizzled LDS fragment address: 64B rows, 16B-unit XOR swizzle
__device__ inline const uchar* laddr(const uchar* base, int row, int kb) {
    int ps = (kb >> 4) ^ ((row >> 1) & 3) ^ ((row >> 4) & 3);
    return base + row*64 + ps*16 + (kb & 15);
}

// ---------------------------------------------------------------------------
// Kernel A: sampling stage (mixture fields constant over m => unif dead).
// ---------------------------------------------------------------------------
__global__ __launch_bounds__(512) void kA_sample(
    const float* __restrict__ x, const float* __restrict__ z,
    const float* __restrict__ mg, float* __restrict__ feat,
    float* __restrict__ flp)
{
    int b = blockIdx.x;
    int n = threadIdx.x;
    int g = n >> 5;
    float mux = mg[g*6+1];
    float muy = mg[g*6+2];
    float sxv = expf(mg[g*6+3]);
    float syv = expf(mg[g*6+4]);
    float rho = tanhf(mg[g*6+5]);
    float z1 = z[((size_t)b*Nx + n)*2 + 0];
    float z2 = z[((size_t)b*Nx + n)*2 + 1];
    float omr2 = 1.0f - rho*rho;
    float xs = mux + sxv*z1;
    float ys = muy + syv*(rho*z1 + sqrtf(omr2)*z2);
    float dx = xs - mux, dy = ys - muy;
    float quad = (dx*dx/(sxv*sxv) - 2.0f*rho*dx*dy/(sxv*syv) + dy*dy/(syv*syv)) / omr2;
    float logprob = -1.8378770664093453f - logf(sxv*syv) - 0.5f*logf(omr2) - 0.5f*quad;
    float lx = tanhf(xs), ly = tanhf(ys);
    int px = (int)truncf(0.5f*(lx+1.0f)*(float)Hx - 0.1f);
    int py = (int)truncf(0.5f*(ly+1.0f)*(float)Hx - 0.1f);
    px = px < 0 ? 0 : (px > Hx-1 ? Hx-1 : px);
    py = py < 0 ? 0 : (py > Hx-1 ? Hx-1 : py);
    float pv = x[(size_t)b*Hx*Hx + (size_t)px*Hx + py];
    size_t fo = ((size_t)b*Nx + n)*3;
    feat[fo+0] = pv; feat[fo+1] = lx; feat[fo+2] = ly;

    __shared__ float red[512];
    red[n] = logprob;
    __syncthreads();
    for (int st = 256; st > 0; st >>= 1) {
        if (n < st) red[n] += red[n+st];
        __syncthreads();
    }
    if (n == 0) flp[b] = red[0];
}

// ---------------------------------------------------------------------------
// Prep: c1,c2 -> fp8 (x16 scale); w2 -> w2t fp8 (x16, transposed).
// ---------------------------------------------------------------------------
__global__ __launch_bounds__(256) void kPrep(
    const float* __restrict__ c1, const float* __restrict__ c2,
    const float* __restrict__ w2,
    uchar* __restrict__ c1q, uchar* __restrict__ c2q, uchar* __restrict__ w2tq)
{
    int idx = blockIdx.x*256 + threadIdx.x;
    if (idx < SIGx*Nx) {
        c1q[idx] = f2fp8(16.0f * c1[idx]);
        c2q[idx] = f2fp8(16.0f * c2[idx]);
    }
    if (idx < HIDx*HIDx) {
        int i = idx >> 8, j = idx & 255;
        w2tq[idx] = f2fp8(16.0f * w2[j*HIDx + i]);
    }
}

// ===========================================================================
// kFuse1S: SPLIT version -- grid (BC, 2): each block handles 256 n-columns
// (all 512 m). 2 blocks/CU -> 4 waves/SIMD for the rcp-bound m-loop (was 2).
// Thread map: tq = t&63 (64 col-quads), mc = t>>6 (8 m-chunks of 64).
// adj and s1t values bit-identical to the unsplit version.
// ===========================================================================
__global__ __launch_bounds__(512) void kFuse1S(
    const float* __restrict__ featL, const float* __restrict__ w1,
    const float* __restrict__ b1,
    uchar* __restrict__ adjAll, uchar* __restrict__ s1tAll)
{
    int b = blockIdx.x;
    int n0 = blockIdx.y * 256;          // column half
    const float* fb = featL + (size_t)b*Nx*3;
    uchar* adj = adjAll + (size_t)b*Nx*Nx;
    uchar* s1t = s1tAll + (size_t)b*HIDx*Nx;

    __shared__ float fpv[Nx], flx[Nx], fly[Nx], fH[Nx];
    __shared__ float w1s[3*HIDx], b1s[HIDx];
    __shared__ float Gp[8][3][256];

    int t = threadIdx.x;
    {
        float pv = fb[t*3+0], lx = fb[t*3+1], ly = fb[t*3+2];
        fpv[t] = pv; flx[t] = lx; fly[t] = ly;
        fH[t] = fmaf(0.5f*lx, lx, fmaf(0.5f*ly, ly, 1.0f));
    }
    for (int i = t; i < 3*HIDx; i += 512) w1s[i] = w1[i];
    if (t < HIDx) b1s[t] = b1[t];
    __syncthreads();

    int tq = t & 63;           // column-quad: local cols lc = 4*tq .. +3
    int mc = t >> 6;           // m-chunk 0..7 (64 m each); wave-uniform
    int lc = tq*4;
    int n4 = n0 + lc;          // global column base

    float xn[4], yn[4], cn[4];
    #pragma unroll
    for (int e = 0; e < 4; ++e) {
        xn[e] = flx[n4+e]; yn[e] = fly[n4+e];
        cn[e] = fmaf(0.5f*xn[e], xn[e], 0.5f*yn[e]*yn[e]);
    }
    float G0[4] = {}, G1[4] = {}, G2[4] = {};

    int m0 = mc*64;
    #pragma unroll 4
    for (int mm = 0; mm < 64; ++mm) {
        int m = m0 + mm;
        float hx = fH[m], fx = flx[m], fy = fly[m];
        float a[4];
        #pragma unroll
        for (int e = 0; e < 4; ++e) {
            float s = fmaf(-yn[e], fy, fmaf(-xn[e], fx, hx + cn[e]));
            a[e] = __builtin_amdgcn_rcpf(s);
            G0[e] = fmaf(a[e], fpv[m], G0[e]);
            G1[e] = fmaf(a[e], fx, G1[e]);
            G2[e] = fmaf(a[e], fy, G2[e]);
        }
        *(uint*)(adj + (size_t)m*Nx + n4) = pk4fp8(a[0], a[1], a[2], a[3]);
    }

    *(f32x4*)&Gp[mc][0][lc] = (f32x4){G0[0],G0[1],G0[2],G0[3]};
    *(f32x4*)&Gp[mc][1][lc] = (f32x4){G1[0],G1[1],G1[2],G1[3]};
    *(f32x4*)&Gp[mc][2][lc] = (f32x4){G2[0],G2[1],G2[2],G2[3]};
    __syncthreads();

    f32x4 T0 = {}, T1 = {}, T2 = {};
    #pragma unroll
    for (int j = 0; j < 8; ++j) {
        T0 += *(const f32x4*)&Gp[j][0][lc];
        T1 += *(const f32x4*)&Gp[j][1][lc];
        T2 += *(const f32x4*)&Gp[j][2][lc];
    }

    int hc = mc;               // 8 h-chunks of 32
    #pragma unroll 4
    for (int hh = 0; hh < 32; ++hh) {
        int h = hc*32 + hh;
        float w0 = w1s[h], wA = w1s[HIDx+h], wB = w1s[2*HIDx+h], bb = b1s[h];
        float v0 = fminf(fmaxf(fmaf(T0.x,w0, fmaf(T1.x,wA, fmaf(T2.x,wB, bb))), 0.0f), 448.0f);
        float v1 = fminf(fmaxf(fmaf(T0.y,w0, fmaf(T1.y,wA, fmaf(T2.y,wB, bb))), 0.0f), 448.0f);
        float v2 = fminf(fmaxf(fmaf(T0.z,w0, fmaf(T1.z,wA, fmaf(T2.z,wB, bb))), 0.0f), 448.0f);
        float v3 = fminf(fmaxf(fmaf(T0.w,w0, fmaf(T1.w,wA, fmaf(T2.w,wB, bb))), 0.0f), 448.0f);
        *(uint*)(s1t + (size_t)h*Nx + n4) = pk4fp8(v0, v1, v2, v3);
    }
}

// ===========================================================================
// kGemmAdj8: s2t[h][n] = 0.25*relu(sum_m h2t[h][m]*adj[m][n]+b2[h]).
// 8-wave, 2-buffer counted-vmcnt (round-6 form; locally converged).
// ===========================================================================
__global__ __launch_bounds__(512, 4) void kGemmAdj8(
    const uchar* __restrict__ Aall, const uchar* __restrict__ adjAll,
    const float* __restrict__ bias, uchar* __restrict__ outAll)
{
    int b    = blockIdx.x;
    int tile = blockIdx.y;
    int rt = tile >> 2;
    int ct = tile & 3;
    const uchar* A = Aall + (size_t)b*HIDx*Nx;
    const uchar* Badj = adjAll + (size_t)b*Nx*Nx;
    uchar* outp = outAll + (size_t)b*HIDx*Nx;

    __shared__ __align__(16) uchar Als[2][128*64];
    __shared__ __align__(16) uchar Bls[2][128*64];
    int t = threadIdx.x;
    int lane = t & 63, wave = t >> 6;
    int wr = wave >> 2, wc = wave & 3;       // 2x4 wave grid, 64x32 each
    int q = lane >> 4, c16 = lane & 15;
    int r0 = rt*128, n0 = ct*128;
    int srow = wave*16 + (lane >> 2);        // staging row (one chunk/wave)
    int pu   = lane & 3;
    int sl   = pu ^ ((srow>>1)&3) ^ ((srow>>4)&3);
    f32x4 acc[4][2] = {};

    auto stage = [&](int buf, int kkv) {     // 2 loads per thread
        gload_lds16(A + (size_t)(r0+srow)*Nx + kkv + sl*16, Als[buf] + wave*1024);
        gload_lds16(Badj + (size_t)(n0+srow)*Nx + kkv + sl*16, Bls[buf] + wave*1024);
    };

    const int nt = Nx/64;      // 8
    stage(0, 0);
    for (int i = 0; i < nt; ++i) {
        if (i < nt-1) { stage((i+1)&1, (i+1)*64); WAITVM(2); }
        else WAITVM(0);
        __builtin_amdgcn_s_barrier();
        MEMFENCE();
        const uchar* Ac = Als[i&1];
        const uchar* Bc = Bls[i&1];
        #pragma unroll
        for (int ks = 0; ks < 64; ks += 32) {
            fp8x8 af[4], bfr[2];
            #pragma unroll
            for (int i2 = 0; i2 < 4; ++i2)
                af[i2] = *(const fp8x8*)laddr(Ac, wr*64 + i2*16 + c16, ks + q*8);
            #pragma unroll
            for (int j = 0; j < 2; ++j)
                bfr[j] = *(const fp8x8*)laddr(Bc, wc*32 + j*16 + c16, ks + q*8);
            #pragma unroll
            for (int i2 = 0; i2 < 4; ++i2)
                #pragma unroll
                for (int j = 0; j < 2; ++j)
                    acc[i2][j] = __builtin_amdgcn_mfma_f32_16x16x32_fp8_fp8(af[i2], bfr[j], acc[i2][j], 0, 0, 0);
        }
        MEMFENCE();
        __builtin_amdgcn_s_barrier();        // write-after-read protect
        MEMFENCE();
    }
    #pragma unroll
    for (int i = 0; i < 4; ++i) {
        int rowb = r0 + wr*64 + i*16 + q*4;
        #pragma unroll
        for (int j = 0; j < 2; ++j) {
            int col = n0 + wc*32 + j*16 + c16;
            #pragma unroll
            for (int r = 0; r < 4; ++r) {
                float v = fmaxf(acc[i][j][r] + bias[rowb + r], 0.0f) * 0.25f;
                outp[(size_t)(rowb + r)*Nx + col] = f2fp8(fminf(v, 448.0f));
            }
        }
    }
}

// ===========================================================================
// kGstd8: C[row][col] = oscale * sum_k A[row][k]*B[k][col]; K=512, NC=256.
// Same 8-wave / acc[4][2] / 2-buffer counted-vmcnt structure as kGemmAdj8.
// ===========================================================================
__global__ __launch_bounds__(512, 4) void kGstd8(
    const uchar* __restrict__ Ash, const uchar* __restrict__ Ball,
    uchar* __restrict__ outAll, float oscale)
{
    int b    = blockIdx.x;
    int tile = blockIdx.y;                   // 0..3
    int rt = tile >> 1;
    int ct = tile & 1;
    const uchar* B = Ball + (size_t)b*HIDx*Nx;
    uchar* outp = outAll + (size_t)b*HIDx*256;

    __shared__ __align__(16) uchar Als[2][128*64];
    __shared__ __align__(16) uchar Bls[2][128*64];
    int t = threadIdx.x;
    int lane = t & 63, wave = t >> 6;
    int wr = wave >> 2, wc = wave & 3;
    int q = lane >> 4, c16 = lane & 15;
    int r0 = rt*128, n0 = ct*128;
    int srow = wave*16 + (lane >> 2);
    int pu   = lane & 3;
    int sl   = pu ^ ((srow>>1)&3) ^ ((srow>>4)&3);
    f32x4 acc[4][2] = {};

    auto stage = [&](int buf, int kkv) {
        gload_lds16(Ash + (size_t)(r0+srow)*Nx + kkv + sl*16, Als[buf] + wave*1024);
        gload_lds16(B + (size_t)(n0+srow)*Nx + kkv + sl*16, Bls[buf] + wave*1024);
    };

    const int nt = Nx/64;      // 8
    stage(0, 0);
    for (int i = 0; i < nt; ++i) {
        if (i < nt-1) { stage((i+1)&1, (i+1)*64); WAITVM(2); }
        else WAITVM(0);
        __builtin_amdgcn_s_barrier();
        MEMFENCE();
        const uchar* Ac = Als[i&1];
        const uchar* Bc = Bls[i&1];
        #pragma unroll
        for (int ks = 0; ks < 64; ks += 32) {
            fp8x8 af[4], bfr[2];
            #pragma unroll
            for (int i2 = 0; i2 < 4; ++i2)
                af[i2] = *(const fp8x8*)laddr(Ac, wr*64 + i2*16 + c16, ks + q*8);
            #pragma unroll
            for (int j = 0; j < 2; ++j)
                bfr[j] = *(const fp8x8*)laddr(Bc, wc*32 + j*16 + c16, ks + q*8);
            #pragma unroll
            for (int i2 = 0; i2 < 4; ++i2)
                #pragma unroll
                for (int j = 0; j < 2; ++j)
                    acc[i2][j] = __builtin_amdgcn_mfma_f32_16x16x32_fp8_fp8(af[i2], bfr[j], acc[i2][j], 0, 0, 0);
        }
        MEMFENCE();
        __builtin_amdgcn_s_barrier();
        MEMFENCE();
    }
    #pragma unroll
    for (int i = 0; i < 4; ++i) {
        int rowb = r0 + wr*64 + i*16 + q*4;
        #pragma unroll
        for (int j = 0; j < 2; ++j) {
            int col = n0 + wc*32 + j*16 + c16;
            #pragma unroll
            for (int r = 0; r < 4; ++r) {
                float v = acc[i][j][r] * oscale;
                v = fminf(fmaxf(v, -448.0f), 448.0f);
                outp[(size_t)(rowb + r)*256 + col] = f2fp8(v);
            }
        }
    }
}

// ===========================================================================
// kGstdT8: h2[h][n] = oscale * sum_k w2t[h][k] * s1t[n-col][k]-transposed.
// 8-WAVE TRB (round-6 form).
// ===========================================================================
__global__ __launch_bounds__(512, 4) void kGstdT8(
    const uchar* __restrict__ Ash, const uchar* __restrict__ Ball,
    uchar* __restrict__ outAll, float oscale)
{
    const int K = 256, NC = 512;
    int b    = blockIdx.x;
    int tile = blockIdx.y;          // 0..7
    int rt = tile >> 2;             // 0..1
    int ct = tile & 3;              // 0..3
    const uchar* B = Ball + (size_t)b*HIDx*Nx;   // s1t: 256 rows x 512
    uchar* outp = outAll + (size_t)b*HIDx*NC;

    __shared__ __align__(16) uchar Als[2][128*64];
    __shared__ __align__(16) uchar Bls[2][128*64];
    int t = threadIdx.x;
    int lane = t & 63, wave = t >> 6;
    int wr = wave >> 2, wc = wave & 3;
    int q = lane >> 4, c16 = lane & 15;
    int r0 = rt*128, n0 = ct*128;
    int srow = wave*16 + (lane >> 2);
    int pu   = lane & 3;
    int sl   = pu ^ ((srow>>1)&3) ^ ((srow>>4)&3);
    int pi  = t & 31;               // k-pair within 64-k tile
    int g   = t >> 5;               // 0..15
    int nc8 = g & 7;                // col group of 16
    int ch  = g >> 3;               // 8-col half within group
    f32x4 acc[4][2] = {};

    auto stageA = [&](int buf, int kkv) {
        gload_lds16(Ash + (size_t)(r0+srow)*K + kkv + sl*16, Als[buf] + wave*1024);
    };
    auto loadBT = [&](int kkv, uint2v& v0, uint2v& v1) {
        int hk = kkv + 2*pi;
        const uchar* g0 = B + (size_t)hk*NC + n0 + nc8*16 + ch*8;
        v0 = *(const uint2v*)g0;
        v1 = *(const uint2v*)(g0 + NC);
    };
    auto writeBT = [&](int buf, const uint2v& v0, const uint2v& v1) {
        const uchar* pa = (const uchar*)&v0;
        const uchar* qa = (const uchar*)&v1;
        int kb = 2*pi;
        int s  = kb >> 4;
        #pragma unroll
        for (int e = 0; e < 8; ++e) {
            int row = nc8*16 + ch*8 + e;
            int ps = s ^ ((row>>1)&3) ^ ((row>>4)&3);
            *(ushort*)(Bls[buf] + row*64 + ps*16 + (kb & 15)) =
                (ushort)pa[e] | ((ushort)qa[e] << 8);
        }
    };
    auto mfmaStep = [&](int buf) {
        const uchar* Ac = Als[buf];
        const uchar* Bc = Bls[buf];
        #pragma unroll
        for (int ks = 0; ks < 64; ks += 32) {
            fp8x8 af[4], bfr[2];
            #pragma unroll
            for (int i = 0; i < 4; ++i)
                af[i] = *(const fp8x8*)laddr(Ac, wr*64 + i*16 + c16, ks + q*8);
            #pragma unroll
            for (int j = 0; j < 2; ++j)
                bfr[j] = *(const fp8x8*)laddr(Bc, wc*32 + j*16 + c16, ks + q*8);
            #pragma unroll
            for (int i = 0; i < 4; ++i)
                #pragma unroll
                for (int j = 0; j < 2; ++j)
                    acc[i][j] = __builtin_amdgcn_mfma_f32_16x16x32_fp8_fp8(af[i], bfr[j], acc[i][j], 0, 0, 0);
        }
    };

    uint2v bv0, bv1;
    stageA(0, 0);
    loadBT(0, bv0, bv1); writeBT(0, bv0, bv1);
    __syncthreads();
    for (int kk = 0; kk < K; kk += 64) {
        int cur = (kk >> 6) & 1, nxt = cur ^ 1;
        bool more = (kk + 64) < K;
        if (more) {
            stageA(nxt, kk + 64);
            loadBT(kk + 64, bv0, bv1);   // regs; written after MFMAs
        }
        mfmaStep(cur);
        if (more) writeBT(nxt, bv0, bv1);
        __syncthreads();
    }
    #pragma unroll
    for (int i = 0; i < 4; ++i) {
        int rowb = r0 + wr*64 + i*16 + q*4;
        #pragma unroll
        for (int j = 0; j < 2; ++j) {
            int col = n0 + wc*32 + j*16 + c16;
            #pragma unroll
            for (int r = 0; r < 4; ++r) {
                float v = acc[i][j][r] * oscale;
                v = fminf(fmaxf(v, -448.0f), 448.0f);
                outp[(size_t)(rowb + r)*NC + col] = f2fp8(v);
            }
        }
    }
}

// ---------------------------------------------------------------------------
// F1: single-pass online softmax-over-b stats for fp8 t1,t2. m and 1/d out.
// ---------------------------------------------------------------------------
__global__ __launch_bounds__(512) void kF1q(
    const uchar* __restrict__ t1, const uchar* __restrict__ t2,
    float* __restrict__ m1, float* __restrict__ rd1,
    float* __restrict__ m2, float* __restrict__ rd2)
{
    int s = blockIdx.x;
    int t = threadIdx.x;
    int hq = t & 63;
    int bq = t >> 6;
    const size_t str = (size_t)SIGx*HIDx;
    size_t base = (size_t)(bq*32)*str + (size_t)s*HIDx + hq*4;

    float mv1[4], dv1[4], mv2[4], dv2[4];
    #pragma unroll
    for (int e = 0; e < 4; ++e) { mv1[e]=-3.0e38f; dv1[e]=0.0f; mv2[e]=-3.0e38f; dv2[e]=0.0f; }

    for (int i = 0; i < 32; ++i) {
        uint u1 = *(const uint*)(t1 + base + (size_t)i*str);
        uint u2 = *(const uint*)(t2 + base + (size_t)i*str);
        float v1[4], v2[4];
        v1[0] = __builtin_amdgcn_cvt_f32_fp8(u1, 0);
        v1[1] = __builtin_amdgcn_cvt_f32_fp8(u1, 1);
        v1[2] = __builtin_amdgcn_cvt_f32_fp8(u1, 2);
        v1[3] = __builtin_amdgcn_cvt_f32_fp8(u1, 3);
        v2[0] = __builtin_amdgcn_cvt_f32_fp8(u2, 0);
        v2[1] = __builtin_amdgcn_cvt_f32_fp8(u2, 1);
        v2[2] = __builtin_amdgcn_cvt_f32_fp8(u2, 2);
        v2[3] = __builtin_amdgcn_cvt_f32_fp8(u2, 3);
        #pragma unroll
        for (int e = 0; e < 4; ++e) {
            float mn;
            mn = fmaxf(mv1[e], v1[e]);
            dv1[e] = dv1[e]*__expf(mv1[e]-mn) + __expf(v1[e]-mn); mv1[e] = mn;
            mn = fmaxf(mv2[e], v2[e]);
            dv2[e] = dv2[e]*__expf(mv2[e]-mn) + __expf(v2[e]-mn); mv2[e] = mn;
        }
    }

    __shared__ float pm1[8][256], pd1[8][256], pm2[8][256], pd2[8][256];
    #pragma unroll
    for (int e = 0; e < 4; ++e) {
        pm1[bq][hq*4+e] = mv1[e]; pd1[bq][hq*4+e] = dv1[e];
        pm2[bq][hq*4+e] = mv2[e]; pd2[bq][hq*4+e] = dv2[e];
    }
    __syncthreads();

    if (t < 256) {
        int h = t;
        float m = -3.0e38f, d = 0.0f;
        #pragma unroll
        for (int j = 0; j < 8; ++j) {
            float mm = pm1[j][h], dd = pd1[j][h];
            float mn = fmaxf(m, mm);
            d = d*__expf(m-mn) + dd*__expf(mm-mn);
            m = mn;
        }
        size_t o = (size_t)s*HIDx + h;
        m1[o] = m; rd1[o] = 1.0f/d;
    } else {
        int h = t - 256;
        float m = -3.0e38f, d = 0.0f;
        #pragma unroll
        for (int j = 0; j < 8; ++j) {
            float mm = pm2[j][h], dd = pd2[j][h];
            float mn = fmaxf(m, mm);
            d = d*__expf(m-mn) + dd*__expf(mm-mn);
            m = mn;
        }
        size_t o = (size_t)s*HIDx + h;
        m2[o] = m; rd2[o] = 1.0f/d;
    }
}

// ---------------------------------------------------------------------------
// F2: sig[b,s] = sum_h exp(t1-m1)*rd1 + exp(t2-m2)*rd2 (fp8 t).
// ---------------------------------------------------------------------------
__global__ __launch_bounds__(256) void kF2q(
    const uchar* __restrict__ t1, const uchar* __restrict__ t2,
    const float* __restrict__ m1, const float* __restrict__ rd1,
    const float* __restrict__ m2, const float* __restrict__ rd2,
    float* __restrict__ sig)
{
    int b = blockIdx.y;
    int sq = threadIdx.x >> 6;
    int s = blockIdx.x*4 + sq;
    int hq = threadIdx.x & 63;
    size_t sh = (size_t)s*HIDx + hq*4;
    size_t tb = ((size_t)b*SIGx + s)*HIDx + hq*4;
    uint u1 = *(const uint*)(t1 + tb);
    uint u2 = *(const uint*)(t2 + tb);
    f32x4 a1 = *(const f32x4*)&m1[sh];
    f32x4 r1 = *(const f32x4*)&rd1[sh];
    f32x4 a2 = *(const f32x4*)&m2[sh];
    f32x4 r2 = *(const f32x4*)&rd2[sh];
    float v = 0.0f;
    v += __expf(__builtin_amdgcn_cvt_f32_fp8(u1,0) - a1.x) * r1.x;
    v += __expf(__builtin_amdgcn_cvt_f32_fp8(u1,1) - a1.y) * r1.y;
    v += __expf(__builtin_amdgcn_cvt_f32_fp8(u1,2) - a1.z) * r1.z;
    v += __expf(__builtin_amdgcn_cvt_f32_fp8(u1,3) - a1.w) * r1.w;
    v += __expf(__builtin_amdgcn_cvt_f32_fp8(u2,0) - a2.x) * r2.x;
    v += __expf(__builtin_amdgcn_cvt_f32_fp8(u2,1) - a2.y) * r2.y;
    v += __expf(__builtin_amdgcn_cvt_f32_fp8(u2,2) - a2.z) * r2.z;
    v += __expf(__builtin_amdgcn_cvt_f32_fp8(u2,3) - a2.w) * r2.w;

    __shared__ float red[256];
    red[threadIdx.x] = v;
    __syncthreads();
    for (int st = 32; st > 0; st >>= 1) {
        if (hq < st) red[threadIdx.x] += red[threadIdx.x + st];
        __syncthreads();
    }
    if (hq == 0) sig[(size_t)b*SIGx + s] = red[sq*64];
}

// ---------------------------------------------------------------------------
// G: out[b,:] = softmax(sig[b,:] @ fcf_w.T + fcf_b)
// Single tree reduction for ALL 10 logits (8 barriers, was 80).
// ---------------------------------------------------------------------------
__global__ __launch_bounds__(256) void kG_out(
    const float* __restrict__ sig, const float* __restrict__ fw,
    const float* __restrict__ fb, float* __restrict__ out)
{
    int b = blockIdx.x;
    int tid = threadIdx.x;
    __shared__ float red[OUTx][257];
    float sv = sig[(size_t)b*SIGx + tid];
    #pragma unroll
    for (int o = 0; o < OUTx; ++o)
        red[o][tid] = sv * fw[o*SIGx + tid];
    __syncthreads();
    for (int st = 128; st > 0; st >>= 1) {
        if (tid < st) {
            #pragma unroll
            for (int o = 0; o < OUTx; ++o)
                red[o][tid] += red[o][tid + st];
        }
        __syncthreads();
    }
    if (tid == 0) {
        float logits[OUTx];
        float mx = -3.0e38f;
        #pragma unroll
        for (int o = 0; o < OUTx; ++o) {
            logits[o] = red[o][0] + fb[o];
            mx = fmaxf(mx, logits[o]);
        }
        float dd = 0.0f; float e[OUTx];
        #pragma unroll
        for (int o = 0; o < OUTx; ++o) { e[o] = expf(logits[o]-mx); dd += e[o]; }
        float inv = 1.0f/dd;
        #pragma unroll
        for (int o = 0; o < OUTx; ++o) out[(size_t)b*OUTx + o] = e[o]*inv;
    }
}

// ---------------------------------------------------------------------------
static inline size_t alignup(size_t b) { return (b + 255) & ~(size_t)255; }

extern "C" void kernel_launch(void* const* d_in, const int* in_sizes, int n_in,
                              void* d_out, int out_size, void* d_ws, size_t ws_size,
                              hipStream_t stream)
{
    const float* x   = (const float*)d_in[0];
    // d_in[1] = unif -- dead
    const float* z   = (const float*)d_in[2];
    const float* mg  = (const float*)d_in[3];
    const float* w1  = (const float*)d_in[4];
    const float* b1  = (const float*)d_in[5];
    const float* w2  = (const float*)d_in[6];
    const float* b2  = (const float*)d_in[7];
    const float* c1  = (const float*)d_in[8];
    const float* c2  = (const float*)d_in[9];
    const float* fw  = (const float*)d_in[10];
    const float* fbv = (const float*)d_in[11];
    float* out = (float*)d_out;
    float* flp = out + (size_t)Bx*OUTx;
    (void)in_sizes; (void)n_in; (void)out_size;

    char* ws = (char*)d_ws;
    size_t off = 0;
    auto alloc = [&](size_t bytes) -> char* {
        char* p = ws + off; off += alignup(bytes); return p;
    };
    float*  feat = (float*)alloc((size_t)Bx*Nx*3*4);
    uchar*  c1q  = (uchar*)alloc((size_t)SIGx*Nx);
    uchar*  c2q  = (uchar*)alloc((size_t)SIGx*Nx);
    uchar*  w2tq = (uchar*)alloc((size_t)HIDx*HIDx);
    uchar*  t1   = (uchar*)alloc((size_t)Bx*SIGx*HIDx);   // fp8 t
    uchar*  t2   = (uchar*)alloc((size_t)Bx*SIGx*HIDx);
    float*  m1   = (float*)alloc((size_t)SIGx*HIDx*4);
    float*  d1   = (float*)alloc((size_t)SIGx*HIDx*4);
    float*  m2   = (float*)alloc((size_t)SIGx*HIDx*4);
    float*  d2   = (float*)alloc((size_t)SIGx*HIDx*4);
    float*  sig  = (float*)alloc((size_t)Bx*SIGx*4);
    size_t fixed = off;

    int BC = 1;
    for (int c = Bx; c >= 1; c >>= 1) {
        size_t need = fixed + alignup((size_t)c*Nx*Nx)
                            + 2*alignup((size_t)c*HIDx*Nx);
        if (need <= ws_size) { BC = c; break; }
    }
    uchar* Padj = (uchar*)alloc((size_t)BC*Nx*Nx);       // adj fp8
    uchar* P1   = (uchar*)alloc((size_t)BC*HIDx*Nx);     // h2q
    uchar* P2   = (uchar*)alloc((size_t)BC*HIDx*Nx);     // s1q / s2q

    hipLaunchKernelGGL(kA_sample, dim3(Bx), dim3(Nx), 0, stream, x, z, mg, feat, flp);
    hipLaunchKernelGGL(kPrep, dim3(512), dim3(256), 0, stream, c1, c2, w2, c1q, c2q, w2tq);

    const int nch = Bx / BC;
    for (int c = 0; c < nch; ++c) {
        int b0 = c * BC;
        const float* featL = feat + (size_t)b0*Nx*3;
        uchar* t1L = t1 + (size_t)b0*SIGx*HIDx;
        uchar* t2L = t2 + (size_t)b0*SIGx*HIDx;
        // adj (fp8) + rank-3 pass-1 -> s1q  (2 blocks per b)
        hipLaunchKernelGGL(kFuse1S, dim3(BC, 2), dim3(512), 0, stream,
                           featL, w1, b1, Padj, P2);
        // t1 = (1/16) * c1q @ s1q -> fp8   (8-wave, 2-buf counted)
        hipLaunchKernelGGL(kGstd8, dim3(BC, 4), dim3(512), 0, stream,
                           c1q, P2, t1L, 0.0625f);
        // h2q = (1/16) * w2tq @ s1q^T-staged -> fp8  (8-wave TRB)
        hipLaunchKernelGGL(kGstdT8, dim3(BC, 8), dim3(512), 0, stream,
                           w2tq, P2, P1, 0.0625f);
        // s2q = 0.25 * relu(h2q @ adj + b2) -> fp8  (8-wave, 2-buf counted)
        hipLaunchKernelGGL(kGemmAdj8, dim3(BC, 8), dim3(512), 0, stream, P1, Padj, b2, P2);
        // t2 = 0.25 * c2q @ s2q  (16 * 1/4 undone) -> fp8
        hipLaunchKernelGGL(kGstd8, dim3(BC, 4), dim3(512), 0, stream,
                           c2q, P2, t2L, 0.25f);
    }

    hipLaunchKernelGGL(kF1q, dim3(SIGx), dim3(512), 0, stream,
                       t1, t2, m1, d1, m2, d2);
    hipLaunchKernelGGL(kF2q, dim3(SIGx/4, Bx), dim3(256), 0, stream,
                       t1, t2, m1, d1, m2, d2, sig);
    hipLaunchKernelGGL(kG_out, dim3(Bx), dim3(256), 0, stream, sig, fw, fbv, out);
}